// Round 1
// baseline (1582.374 us; speedup 1.0000x reference)
//
#include <hip/hip_runtime.h>
#include <math.h>

#define B 4
#define S 1024
#define D 256
#define H 6
#define HD 64
#define NE 3
#define HHD 384
#define ROWS (B*S)

__device__ __forceinline__ float leaky(float x){ return x > 0.f ? x : 0.2f*x; }

// W1 [H,D,HD] -> W1t [D, H*HD]
__global__ __launch_bounds__(256) void transpose_w1_kernel(const float* __restrict__ src,
                                                           float* __restrict__ dst){
    int idx = blockIdx.x*256 + threadIdx.x;           // < D*HHD
    int f = idx / HHD;
    int rem = idx - f*HHD;
    int head = rem >> 6, o = rem & 63;
    dst[idx] = src[(head*D + f)*HD + o];
}

__global__ __launch_bounds__(256) void zero_kernel(float* __restrict__ dep, float* __restrict__ sum){
    int idx = blockIdx.x*256 + threadIdx.x;           // < ROWS*D/4
    ((float4*)dep)[idx] = make_float4(0.f,0.f,0.f,0.f);
    if (idx == 0) *sum = 0.f;
}

// router: logits = x @ router_W [D,NE]; exclude argmin (last-index tie-break)
__global__ __launch_bounds__(256) void router_kernel(const float* __restrict__ x,
                                                     const float* __restrict__ rw,
                                                     float* __restrict__ rmask){
    int wave = threadIdx.x >> 6, lane = threadIdx.x & 63;
    int row = blockIdx.x*4 + wave;
    float4 xv = ((const float4*)(x + row*D))[lane];
    int f = lane*4;
    float xa[4] = {xv.x, xv.y, xv.z, xv.w};
    float p0 = 0.f, p1 = 0.f, p2 = 0.f;
    #pragma unroll
    for (int j = 0; j < 4; j++){
        p0 += xa[j]*rw[(f+j)*NE + 0];
        p1 += xa[j]*rw[(f+j)*NE + 1];
        p2 += xa[j]*rw[(f+j)*NE + 2];
    }
    for (int off = 32; off; off >>= 1){
        p0 += __shfl_down(p0, off);
        p1 += __shfl_down(p1, off);
        p2 += __shfl_down(p2, off);
    }
    if (lane == 0){
        float p[3] = {p0, p1, p2};
        int ex = 0;
        for (int e = 1; e < NE; e++) if (p[e] <= p[ex]) ex = e;
        for (int e = 0; e < NE; e++) rmask[e*ROWS + row] = (e == ex) ? 0.f : 1.f;
    }
}

// out[row, n] = sum_k X[row,k] * W[k,n]; 16 rows per block, optional per-row scale
template<int K, int N>
__global__ __launch_bounds__(256) void gemm16_kernel(const float* __restrict__ X,
                                                     const float* __restrict__ W,
                                                     const float* __restrict__ rowscale,
                                                     float* __restrict__ outp){
    __shared__ float lds_x[16*(K+4)];
    int tid = threadIdx.x;
    int row0 = blockIdx.x*16;
    const float4* xs = (const float4*)(X + (size_t)row0*K);
    constexpr int KF4 = K/4;
    for (int i = tid; i < 16*KF4; i += 256){
        int rr = i / KF4, cc = i - rr*KF4;
        float4 v = xs[i];
        if (rowscale){
            float m = rowscale[row0 + rr];
            v.x *= m; v.y *= m; v.z *= m; v.w *= m;
        }
        ((float4*)(lds_x + rr*(K+4)))[cc] = v;
    }
    __syncthreads();
    int r = tid >> 4, g = tid & 15;
    constexpr int NQ = N/64;
    float4 acc[NQ];
    #pragma unroll
    for (int q = 0; q < NQ; q++) acc[q] = make_float4(0.f,0.f,0.f,0.f);
    const float* xrow = lds_x + r*(K+4);
    for (int k = 0; k < K; k++){
        float xv = xrow[k];
        const float4* wrow = (const float4*)(W + (size_t)k*N);
        #pragma unroll
        for (int q = 0; q < NQ; q++){
            float4 w = wrow[g + 16*q];
            acc[q].x += xv*w.x; acc[q].y += xv*w.y; acc[q].z += xv*w.z; acc[q].w += xv*w.w;
        }
    }
    float4* orow = (float4*)(outp + (size_t)(row0 + r)*N);
    #pragma unroll
    for (int q = 0; q < NQ; q++) orow[g + 16*q] = acc[q];
}

// es/ed: per (b,s) row, per head: dot(h[row, head*64..], a1)
__global__ __launch_bounds__(256) void esed_kernel(const float* __restrict__ hbuf,
                                                   const float* __restrict__ a1s,
                                                   const float* __restrict__ a1d,
                                                   float* __restrict__ es, float* __restrict__ ed){
    int wave = threadIdx.x >> 6, lane = threadIdx.x & 63;
    int row = blockIdx.x*4 + wave;
    int b = row >> 10, s = row & 1023;
    const float* hrow = hbuf + (size_t)row*HHD;
    for (int head = 0; head < H; head++){
        float v = hrow[head*HD + lane];
        float ps = v*a1s[head*HD + lane];
        float pd = v*a1d[head*HD + lane];
        for (int off = 32; off; off >>= 1){
            ps += __shfl_down(ps, off);
            pd += __shfl_down(pd, off);
        }
        if (lane == 0){
            es[(b*H + head)*S + s] = ps;
            ed[(b*H + head)*S + s] = pd;
        }
    }
}

// layer-1 attention + ELU, writes concat layout h1c[b,s,head*64+o]
__global__ __launch_bounds__(256) void attn1_kernel(const float* __restrict__ hbuf,
                                                    const float* __restrict__ es,
                                                    const float* __restrict__ ed,
                                                    const float* __restrict__ adj,
                                                    float* __restrict__ h1c,
                                                    const int* __restrict__ doc_p,
                                                    const int* __restrict__ sect_p,
                                                    int expert){
    __shared__ float lds_h[64*64];
    __shared__ float lds_w[16*65];
    __shared__ float lds_pm[256];
    __shared__ float lds_m[16];
    int tid = threadIdx.x;
    int s0 = blockIdx.x*16, head = blockIdx.y, b = blockIdx.z;
    int tlo = 0, thi = S;
    if (expert == 0) { thi = S - *sect_p - *doc_p; }
    else if (expert == 1) { tlo = S - *sect_p - *doc_p; thi = S - *doc_p; }
    else if (expert == 2) { tlo = S - *doc_p; }
    int r = tid >> 4, g = tid & 15;
    int bh = b*H + head;
    float es_r = es[bh*S + s0 + r];
    const float* adjrow = adj + (size_t)(b*S + s0 + r)*S;
    const float* edrow = ed + bh*S;
    // phase A: row max of masked leaky(es+ed)
    float m = -1e9f;
    for (int i = 0; i < 16; i++){
        int t = i*64 + g*4;
        float4 a4 = *(const float4*)(adjrow + t);
        float4 e4 = *(const float4*)(edrow + t);
        float as[4] = {a4.x,a4.y,a4.z,a4.w};
        float ev[4] = {e4.x,e4.y,e4.z,e4.w};
        #pragma unroll
        for (int j = 0; j < 4; j++){
            int tj = t + j;
            bool msk = (tj >= tlo) && (tj < thi) && (as[j] > 0.f);
            float v = leaky(es_r + ev[j]);
            m = fmaxf(m, msk ? v : -1e9f);
        }
    }
    lds_pm[tid] = m;
    __syncthreads();
    if (tid < 16){
        float mm = -1e9f;
        for (int j = 0; j < 16; j++) mm = fmaxf(mm, lds_pm[tid*16 + j]);
        lds_m[tid] = mm;
    }
    __syncthreads();
    float m_r = lds_m[r];
    float4 acc = make_float4(0.f,0.f,0.f,0.f);
    float denom = 0.f;
    const float* hbase = hbuf + (size_t)b*S*HHD + head*HD;
    for (int t0 = 0; t0 < S; t0 += 64){
        if (t0) __syncthreads();
        for (int i = tid; i < 1024; i += 256){           // 64x64 floats as float4
            int tt = i >> 4, off = i & 15;
            ((float4*)lds_h)[i] = *(const float4*)(hbase + (size_t)(t0 + tt)*HHD + off*4);
        }
        {
            int t = t0 + g*4;
            float4 a4 = *(const float4*)(adjrow + t);
            float4 e4 = *(const float4*)(edrow + t);
            float as[4] = {a4.x,a4.y,a4.z,a4.w};
            float ev[4] = {e4.x,e4.y,e4.z,e4.w};
            #pragma unroll
            for (int j = 0; j < 4; j++){
                int tj = t + j;
                bool msk = (tj >= tlo) && (tj < thi) && (as[j] > 0.f);
                float e_ = msk ? leaky(es_r + ev[j]) : -1e9f;
                lds_w[r*65 + g*4 + j] = __expf(e_ - m_r);
            }
        }
        __syncthreads();
        #pragma unroll 4
        for (int tt = 0; tt < 64; tt++){
            float w = lds_w[r*65 + tt];
            denom += w;
            float4 hv = ((float4*)lds_h)[tt*16 + g];
            acc.x += w*hv.x; acc.y += w*hv.y; acc.z += w*hv.z; acc.w += w*hv.w;
        }
    }
    float inv = 1.f/denom;
    acc.x *= inv; acc.y *= inv; acc.z *= inv; acc.w *= inv;
    float4 outv;
    outv.x = acc.x > 0.f ? acc.x : __expf(acc.x) - 1.f;
    outv.y = acc.y > 0.f ? acc.y : __expf(acc.y) - 1.f;
    outv.z = acc.z > 0.f ? acc.z : __expf(acc.z) - 1.f;
    outv.w = acc.w > 0.f ? acc.w : __expf(acc.w) - 1.f;
    *(float4*)(h1c + (size_t)(b*S + s0 + r)*HHD + head*HD + g*4) = outv;
}

// f2s/f2d: dot(h2[row], a2s/a2d), 256-wide
__global__ __launch_bounds__(256) void f2dots_kernel(const float* __restrict__ h2,
                                                     const float* __restrict__ a2s,
                                                     const float* __restrict__ a2d,
                                                     float* __restrict__ f2s, float* __restrict__ f2d){
    int wave = threadIdx.x >> 6, lane = threadIdx.x & 63;
    int row = blockIdx.x*4 + wave;
    float4 hv = ((const float4*)(h2 + (size_t)row*D))[lane];
    float4 s4 = ((const float4*)a2s)[lane];
    float4 d4 = ((const float4*)a2d)[lane];
    float ps = hv.x*s4.x + hv.y*s4.y + hv.z*s4.z + hv.w*s4.w;
    float pd = hv.x*d4.x + hv.y*d4.y + hv.z*d4.z + hv.w*d4.w;
    for (int off = 32; off; off >>= 1){
        ps += __shfl_down(ps, off);
        pd += __shfl_down(pd, off);
    }
    if (lane == 0){ f2s[row] = ps; f2d[row] = pd; }
}

// layer-2 attention; writes main_out or accumulates rmask*out into dep_acc
__global__ __launch_bounds__(256) void attn2_kernel(const float* __restrict__ h2,
                                                    const float* __restrict__ f2s,
                                                    const float* __restrict__ f2d,
                                                    const float* __restrict__ adj,
                                                    const float* __restrict__ rmask,
                                                    float* __restrict__ outp,
                                                    const int* __restrict__ doc_p,
                                                    const int* __restrict__ sect_p,
                                                    int expert, int accum){
    __shared__ float lds_h[32*256];
    __shared__ float lds_w[16*33];
    __shared__ float lds_pm[256];
    __shared__ float lds_m[16];
    int tid = threadIdx.x, r = tid >> 4, g = tid & 15;
    int s0 = blockIdx.x*16, b = blockIdx.y;
    int tlo = 0, thi = S;
    if (expert == 0) { thi = S - *sect_p - *doc_p; }
    else if (expert == 1) { tlo = S - *sect_p - *doc_p; thi = S - *doc_p; }
    else if (expert == 2) { tlo = S - *doc_p; }
    int row = b*S + s0 + r;
    float fs_r = f2s[row];
    const float* adjrow = adj + (size_t)row*S;
    const float* fdrow = f2d + b*S;
    float m = -1e9f;
    for (int i = 0; i < 16; i++){
        int t = i*64 + g*4;
        float4 a4 = *(const float4*)(adjrow + t);
        float4 e4 = *(const float4*)(fdrow + t);
        float as[4] = {a4.x,a4.y,a4.z,a4.w};
        float ev[4] = {e4.x,e4.y,e4.z,e4.w};
        #pragma unroll
        for (int j = 0; j < 4; j++){
            int tj = t + j;
            bool msk = (tj >= tlo) && (tj < thi) && (as[j] > 0.f);
            float v = leaky(fs_r + ev[j]);
            m = fmaxf(m, msk ? v : -1e9f);
        }
    }
    lds_pm[tid] = m;
    __syncthreads();
    if (tid < 16){
        float mm = -1e9f;
        for (int j = 0; j < 16; j++) mm = fmaxf(mm, lds_pm[tid*16 + j]);
        lds_m[tid] = mm;
    }
    __syncthreads();
    float m_r = lds_m[r];
    float4 acc0 = make_float4(0.f,0.f,0.f,0.f), acc1 = acc0, acc2 = acc0, acc3 = acc0;
    float denom = 0.f;
    const float* hb = h2 + (size_t)b*S*D;
    for (int t0 = 0; t0 < S; t0 += 32){
        if (t0) __syncthreads();
        const float4* src = (const float4*)(hb + (size_t)t0*D);
        for (int i = tid; i < 2048; i += 256) ((float4*)lds_h)[i] = src[i];
        #pragma unroll
        for (int j = 0; j < 2; j++){
            int tt = g*2 + j, t = t0 + tt;
            float a = adjrow[t];
            bool msk = (t >= tlo) && (t < thi) && (a > 0.f);
            float e_ = msk ? leaky(fs_r + fdrow[t]) : -1e9f;
            lds_w[r*33 + tt] = __expf(e_ - m_r);
        }
        __syncthreads();
        #pragma unroll 4
        for (int tt = 0; tt < 32; tt++){
            float w = lds_w[r*33 + tt];
            denom += w;
            const float4* hrow = (const float4*)(lds_h + tt*D);
            float4 h0 = hrow[g], h1v = hrow[g+16], h2v = hrow[g+32], h3 = hrow[g+48];
            acc0.x += w*h0.x;  acc0.y += w*h0.y;  acc0.z += w*h0.z;  acc0.w += w*h0.w;
            acc1.x += w*h1v.x; acc1.y += w*h1v.y; acc1.z += w*h1v.z; acc1.w += w*h1v.w;
            acc2.x += w*h2v.x; acc2.y += w*h2v.y; acc2.z += w*h2v.z; acc2.w += w*h2v.w;
            acc3.x += w*h3.x;  acc3.y += w*h3.y;  acc3.z += w*h3.z;  acc3.w += w*h3.w;
        }
    }
    float inv = 1.f/denom;
    acc0.x*=inv; acc0.y*=inv; acc0.z*=inv; acc0.w*=inv;
    acc1.x*=inv; acc1.y*=inv; acc1.z*=inv; acc1.w*=inv;
    acc2.x*=inv; acc2.y*=inv; acc2.z*=inv; acc2.w*=inv;
    acc3.x*=inv; acc3.y*=inv; acc3.z*=inv; acc3.w*=inv;
    float* obase = outp + (size_t)row*D + g*4;
    if (!accum){
        *(float4*)(obase)       = acc0;
        *(float4*)(obase + 64)  = acc1;
        *(float4*)(obase + 128) = acc2;
        *(float4*)(obase + 192) = acc3;
    } else {
        float rm = rmask[row];
        float4 c0 = *(float4*)(obase), c1 = *(float4*)(obase+64),
               c2 = *(float4*)(obase+128), c3 = *(float4*)(obase+192);
        c0.x += rm*acc0.x; c0.y += rm*acc0.y; c0.z += rm*acc0.z; c0.w += rm*acc0.w;
        c1.x += rm*acc1.x; c1.y += rm*acc1.y; c1.z += rm*acc1.z; c1.w += rm*acc1.w;
        c2.x += rm*acc2.x; c2.y += rm*acc2.y; c2.z += rm*acc2.z; c2.w += rm*acc2.w;
        c3.x += rm*acc3.x; c3.y += rm*acc3.y; c3.z += rm*acc3.z; c3.w += rm*acc3.w;
        *(float4*)(obase)       = c0;
        *(float4*)(obase + 64)  = c1;
        *(float4*)(obase + 128) = c2;
        *(float4*)(obase + 192) = c3;
    }
}

// blend gate + final output + sum(blend_weight)
__global__ __launch_bounds__(256) void blend_kernel(const float* __restrict__ feat,
                                                    const float* __restrict__ bW,
                                                    const float* __restrict__ bb,
                                                    const float* __restrict__ mainO,
                                                    const float* __restrict__ depO,
                                                    float* __restrict__ outp,
                                                    float* __restrict__ sumBuf){
    __shared__ float lds_x[16*260];
    __shared__ float red[256];
    int tid = threadIdx.x, r = tid >> 4, g = tid & 15;
    int row0 = blockIdx.x*16;
    const float4* xs = (const float4*)(feat + (size_t)row0*D);
    for (int i = tid; i < 16*64; i += 256){
        int rr = i >> 6, cc = i & 63;
        ((float4*)(lds_x + rr*260))[cc] = xs[i];
    }
    __syncthreads();
    float4 acc[4];
    #pragma unroll
    for (int q = 0; q < 4; q++) acc[q] = make_float4(0.f,0.f,0.f,0.f);
    const float* xrow = lds_x + r*260;
    for (int k = 0; k < 256; k++){
        float xv = xrow[k];
        const float4* wrow = (const float4*)(bW + (size_t)k*256);
        #pragma unroll
        for (int q = 0; q < 4; q++){
            float4 w = wrow[g + 16*q];
            acc[q].x += xv*w.x; acc[q].y += xv*w.y; acc[q].z += xv*w.z; acc[q].w += xv*w.w;
        }
    }
    int row = row0 + r;
    float lsum = 0.f;
    #pragma unroll
    for (int q = 0; q < 4; q++){
        int n = g*4 + 64*q;
        float4 bias = *(const float4*)(bb + n);
        float4 mo = *(const float4*)(mainO + (size_t)row*D + n);
        float4 dp = *(const float4*)(depO + (size_t)row*D + n);
        float z[4]  = {acc[q].x + bias.x, acc[q].y + bias.y, acc[q].z + bias.z, acc[q].w + bias.w};
        float mv[4] = {mo.x, mo.y, mo.z, mo.w};
        float dv[4] = {dp.x, dp.y, dp.z, dp.w};
        float4 outv;
        float* ov = (float*)&outv;
        #pragma unroll
        for (int j = 0; j < 4; j++){
            float bw = 1.f/(1.f + __expf(-z[j]));
            lsum += bw;
            ov[j] = bw*mv[j] + (1.f - bw)*dv[j];
        }
        *(float4*)(outp + (size_t)row*D + n) = outv;
    }
    red[tid] = lsum;
    __syncthreads();
    for (int sft = 128; sft; sft >>= 1){
        if (tid < sft) red[tid] += red[tid + sft];
        __syncthreads();
    }
    if (tid == 0) atomicAdd(sumBuf, red[0]);
}

__global__ void finalize_kernel(const float* __restrict__ sumBuf, float* __restrict__ outp){
    float mc = *sumBuf / (float)(ROWS*D);
    outp[ROWS*D]     = fabsf(mc - 0.6f)*0.01f;
    outp[ROWS*D + 1] = mc;
}

extern "C" void kernel_launch(void* const* d_in, const int* in_sizes, int n_in,
                              void* d_out, int out_size, void* d_ws, size_t ws_size,
                              hipStream_t stream)
{
    const float* feature  = (const float*)d_in[0];
    const float* adj      = (const float*)d_in[1];
    const float* main_W1  = (const float*)d_in[2];
    const float* main_a1s = (const float*)d_in[3];
    const float* main_a1d = (const float*)d_in[4];
    const float* main_W2  = (const float*)d_in[5];
    const float* main_a2s = (const float*)d_in[6];
    const float* main_a2d = (const float*)d_in[7];
    const float* dep_W1   = (const float*)d_in[8];
    const float* dep_a1s  = (const float*)d_in[9];
    const float* dep_a1d  = (const float*)d_in[10];
    const float* dep_W2   = (const float*)d_in[11];
    const float* dep_a2s  = (const float*)d_in[12];
    const float* dep_a2d  = (const float*)d_in[13];
    const float* router_W = (const float*)d_in[14];
    const float* blend_W  = (const float*)d_in[15];
    const float* blend_b  = (const float*)d_in[16];
    const int*   doc_p    = (const int*)d_in[17];
    const int*   sect_p   = (const int*)d_in[18];

    float* ws     = (float*)d_ws;
    float* w1t    = ws;                         // 4 * D*HHD
    float* hbuf   = w1t  + 4*D*HHD;             // ROWS*HHD
    float* esb    = hbuf + (size_t)ROWS*HHD;    // B*H*S
    float* edb    = esb  + B*H*S;               // B*H*S
    float* h1c    = edb  + B*H*S;               // ROWS*HHD
    float* h2b    = h1c  + (size_t)ROWS*HHD;    // ROWS*D
    float* f2sb   = h2b  + (size_t)ROWS*D;      // ROWS
    float* f2db   = f2sb + ROWS;                // ROWS
    float* rmask  = f2db + ROWS;                // NE*ROWS
    float* mainO  = rmask + NE*ROWS;            // ROWS*D
    float* depO   = mainO + (size_t)ROWS*D;     // ROWS*D
    float* sumBuf = depO  + (size_t)ROWS*D;     // 1
    float* outp   = (float*)d_out;

    transpose_w1_kernel<<<D*HHD/256, 256, 0, stream>>>(main_W1, w1t);
    for (int e = 0; e < NE; e++)
        transpose_w1_kernel<<<D*HHD/256, 256, 0, stream>>>(dep_W1 + (size_t)e*H*D*HD,
                                                           w1t + (size_t)(e+1)*D*HHD);
    zero_kernel<<<ROWS*D/4/256, 256, 0, stream>>>(depO, sumBuf);
    router_kernel<<<ROWS/4, 256, 0, stream>>>(feature, router_W, rmask);

    // ---- main expert ----
    gemm16_kernel<256,384><<<ROWS/16, 256, 0, stream>>>(feature, w1t, nullptr, hbuf);
    esed_kernel<<<ROWS/4, 256, 0, stream>>>(hbuf, main_a1s, main_a1d, esb, edb);
    attn1_kernel<<<dim3(S/16, H, B), 256, 0, stream>>>(hbuf, esb, edb, adj, h1c, doc_p, sect_p, -1);
    gemm16_kernel<384,256><<<ROWS/16, 256, 0, stream>>>(h1c, main_W2, nullptr, h2b);
    f2dots_kernel<<<ROWS/4, 256, 0, stream>>>(h2b, main_a2s, main_a2d, f2sb, f2db);
    attn2_kernel<<<dim3(S/16, B), 256, 0, stream>>>(h2b, f2sb, f2db, adj, nullptr, mainO,
                                                    doc_p, sect_p, -1, 0);

    // ---- deputy experts ----
    for (int e = 0; e < NE; e++){
        gemm16_kernel<256,384><<<ROWS/16, 256, 0, stream>>>(feature, w1t + (size_t)(e+1)*D*HHD,
                                                            rmask + (size_t)e*ROWS, hbuf);
        esed_kernel<<<ROWS/4, 256, 0, stream>>>(hbuf, dep_a1s + (size_t)e*H*HD,
                                                dep_a1d + (size_t)e*H*HD, esb, edb);
        attn1_kernel<<<dim3(S/16, H, B), 256, 0, stream>>>(hbuf, esb, edb, adj, h1c,
                                                           doc_p, sect_p, e);
        gemm16_kernel<384,256><<<ROWS/16, 256, 0, stream>>>(h1c, dep_W2 + (size_t)e*HHD*D,
                                                            nullptr, h2b);
        f2dots_kernel<<<ROWS/4, 256, 0, stream>>>(h2b, dep_a2s + (size_t)e*D,
                                                  dep_a2d + (size_t)e*D, f2sb, f2db);
        attn2_kernel<<<dim3(S/16, B), 256, 0, stream>>>(h2b, f2sb, f2db, adj,
                                                        rmask + (size_t)e*ROWS, depO,
                                                        doc_p, sect_p, e, 1);
    }

    blend_kernel<<<ROWS/16, 256, 0, stream>>>(feature, blend_W, blend_b, mainO, depO, outp, sumBuf);
    finalize_kernel<<<1, 1, 0, stream>>>(sumBuf, outp);
}

// Round 2
// 815.415 us; speedup vs baseline: 1.9406x; 1.9406x over previous
//
#include <hip/hip_runtime.h>
#include <math.h>

#define B 4
#define S 1024
#define D 256
#define H 6
#define HD 64
#define NE 3
#define HHD 384
#define ROWS (B*S)

typedef __attribute__((ext_vector_type(8))) short bf8_t;
typedef __attribute__((ext_vector_type(8))) unsigned short u16x8;
typedef __attribute__((ext_vector_type(4))) float f32x4;

__device__ __forceinline__ float leaky(float x){ return x > 0.f ? x : 0.2f*x; }

__device__ __forceinline__ unsigned short f2bf(float f){
    union { float f; unsigned int u; } v; v.f = f;
    unsigned int u = v.u;
    unsigned int r = (u + 0x7FFFu + ((u >> 16) & 1u)) >> 16;
    return (unsigned short)r;
}
__device__ __forceinline__ float bf2f(unsigned short h){
    union { unsigned int u; float f; } v; v.u = ((unsigned int)h) << 16;
    return v.f;
}

// ---------- prep kernels ----------
__global__ __launch_bounds__(256) void conv_feat_kernel(const float* __restrict__ src,
                                                        unsigned short* __restrict__ dst){
    int idx = blockIdx.x*256 + threadIdx.x;             // < ROWS*D/4
    float4 v = ((const float4*)src)[idx];
    ushort4 o;
    o.x = f2bf(v.x); o.y = f2bf(v.y); o.z = f2bf(v.z); o.w = f2bf(v.w);
    ((ushort4*)dst)[idx] = o;
}

// w1nk[e][n=h*64+o][k=f] = W1_e[h][f][o]
__global__ __launch_bounds__(256) void prep_w1_kernel(const float* __restrict__ mainW,
                                                      const float* __restrict__ depW,
                                                      unsigned short* __restrict__ dst){
    int e = blockIdx.y;
    const float* src = (e == 0) ? mainW : depW + (size_t)(e-1)*H*D*HD;
    int idx = blockIdx.x*256 + threadIdx.x;             // < HHD*D
    int n = idx >> 8, k = idx & 255;
    int h = n >> 6, o = n & 63;
    dst[(size_t)e*HHD*D + idx] = f2bf(src[(h*D + k)*HD + o]);
}

// w2nk[e][n=d][k] = W2_e[k][d]
__global__ __launch_bounds__(384) void prep_w2_kernel(const float* __restrict__ mainW,
                                                      const float* __restrict__ depW,
                                                      unsigned short* __restrict__ dst){
    int e = blockIdx.y;
    const float* src = (e == 0) ? mainW : depW + (size_t)(e-1)*HHD*D;
    int k = threadIdx.x, n = blockIdx.x;
    dst[((size_t)e*D + n)*HHD + k] = f2bf(src[k*D + n]);
}

// bwt[col][k] = blend_W[k][col]
__global__ __launch_bounds__(256) void prep_bw_kernel(const float* __restrict__ src,
                                                      unsigned short* __restrict__ dst){
    int k = threadIdx.x, col = blockIdx.x;
    dst[col*D + k] = f2bf(src[k*D + col]);
}

__global__ __launch_bounds__(256) void zero_kernel(float* __restrict__ dep, float* __restrict__ sum){
    int idx = blockIdx.x*256 + threadIdx.x;
    ((float4*)dep)[idx] = make_float4(0.f,0.f,0.f,0.f);
    if (idx == 0) *sum = 0.f;
}

__global__ __launch_bounds__(256) void router_kernel(const float* __restrict__ x,
                                                     const float* __restrict__ rw,
                                                     float* __restrict__ rmask){
    int wave = threadIdx.x >> 6, lane = threadIdx.x & 63;
    int row = blockIdx.x*4 + wave;
    float4 xv = ((const float4*)(x + (size_t)row*D))[lane];
    int f = lane*4;
    float xa[4] = {xv.x, xv.y, xv.z, xv.w};
    float p0 = 0.f, p1 = 0.f, p2 = 0.f;
    #pragma unroll
    for (int j = 0; j < 4; j++){
        p0 += xa[j]*rw[(f+j)*NE + 0];
        p1 += xa[j]*rw[(f+j)*NE + 1];
        p2 += xa[j]*rw[(f+j)*NE + 2];
    }
    for (int off = 32; off; off >>= 1){
        p0 += __shfl_down(p0, off);
        p1 += __shfl_down(p1, off);
        p2 += __shfl_down(p2, off);
    }
    if (lane == 0){
        float p[3] = {p0, p1, p2};
        int ex = 0;
        for (int e = 1; e < NE; e++) if (p[e] <= p[ex]) ex = e;
        for (int e = 0; e < NE; e++) rmask[e*ROWS + row] = (e == ex) ? 0.f : 1.f;
    }
}

// ---------- MFMA GEMM, transposed bf16 output ----------
// C[m][n] = sum_k A[m][k]*Bt[n][k]; out stored [b][M][s] (n = b*1024+s), bf16.
template<int K, int M>
__global__ __launch_bounds__(256) void gemm_tn_kernel(const unsigned short* __restrict__ A,
                                                      const unsigned short* __restrict__ Bt,
                                                      const float* __restrict__ rowscale,
                                                      unsigned short* __restrict__ outT){
    int tid = threadIdx.x, wave = tid >> 6, lane = tid & 63;
    int quad = lane >> 4, l16 = lane & 15;
    int m0 = blockIdx.x*64, n0 = blockIdx.y*64;
    const unsigned short* arow = A + (size_t)(m0 + wave*16 + l16)*K + quad*8;
    const unsigned short* brow[4];
    bool zr[4];
    #pragma unroll
    for (int j = 0; j < 4; j++){
        int n = n0 + j*16 + l16;
        brow[j] = Bt + (size_t)n*K + quad*8;
        zr[j] = rowscale ? (rowscale[n] == 0.f) : false;
    }
    f32x4 zero = {0.f,0.f,0.f,0.f};
    f32x4 acc[4] = {zero, zero, zero, zero};
    bf8_t bz = {0,0,0,0,0,0,0,0};
    for (int k0 = 0; k0 < K; k0 += 32){
        bf8_t a = *(const bf8_t*)(arow + k0);
        #pragma unroll
        for (int j = 0; j < 4; j++){
            bf8_t bv = *(const bf8_t*)(brow[j] + k0);
            if (zr[j]) bv = bz;
            acc[j] = __builtin_amdgcn_mfma_f32_16x16x32_bf16(a, bv, acc[j], 0, 0, 0);
        }
    }
    int mbase = m0 + wave*16 + quad*4;
    #pragma unroll
    for (int j = 0; j < 4; j++){
        int ng = n0 + j*16 + l16;
        int b = ng >> 10, s = ng & 1023;
        #pragma unroll
        for (int r = 0; r < 4; r++){
            outT[((size_t)b*M + mbase + r)*S + s] = f2bf(acc[j][r]);
        }
    }
}

// es/ed[bh][s] = sum_o ht[b][h*64+o][s] * a1[h][o]
__global__ __launch_bounds__(256) void esed_kernel(const unsigned short* __restrict__ ht,
                                                   const float* __restrict__ a1s,
                                                   const float* __restrict__ a1d,
                                                   float* __restrict__ es, float* __restrict__ ed){
    int bh = blockIdx.x;
    int b = bh / H, h = bh - b*H;
    int s = blockIdx.y*256 + threadIdx.x;
    const unsigned short* base = ht + ((size_t)b*HHD + h*64)*S + s;
    float ps = 0.f, pd = 0.f;
    #pragma unroll 8
    for (int o = 0; o < 64; o++){
        float hv = bf2f(base[(size_t)o*S]);
        ps += hv*a1s[h*64 + o];
        pd += hv*a1d[h*64 + o];
    }
    es[(size_t)bh*S + s] = ps;
    ed[(size_t)bh*S + s] = pd;
}

// column means of [C][S] bf16: mean[c] = (1/S) sum_s src[c][s]
__global__ __launch_bounds__(256) void colmean_kernel(const unsigned short* __restrict__ src,
                                                      float* __restrict__ mean){
    int wave = threadIdx.x >> 6, lane = threadIdx.x & 63;
    int c = blockIdx.x*4 + wave;
    const unsigned short* p = src + (size_t)c*S + lane*16;
    u16x8 v0 = *(const u16x8*)p;
    u16x8 v1 = *(const u16x8*)(p + 8);
    float sum = 0.f;
    #pragma unroll
    for (int j = 0; j < 8; j++) sum += bf2f(v0[j]) + bf2f(v1[j]);
    for (int off = 32; off; off >>= 1) sum += __shfl_down(sum, off);
    if (lane == 0) mean[c] = sum * (1.f/(float)S);
}

// f2s/f2d[b][s] = sum_c h2t[b][c][s] * a2[c]
__global__ __launch_bounds__(256) void f2dots_kernel(const unsigned short* __restrict__ h2t,
                                                     const float* __restrict__ a2s,
                                                     const float* __restrict__ a2d,
                                                     float* __restrict__ f2s, float* __restrict__ f2d){
    int b = blockIdx.x;
    int s = blockIdx.y*256 + threadIdx.x;
    const unsigned short* base = h2t + (size_t)b*D*S + s;
    float ps = 0.f, pd = 0.f;
    #pragma unroll 8
    for (int c = 0; c < D; c++){
        float hv = bf2f(base[(size_t)c*S]);
        ps += hv*a2s[c];
        pd += hv*a2d[c];
    }
    f2s[b*S + s] = ps;
    f2d[b*S + s] = pd;
}

// ---------- layer-1 attention: 6 heads fused, MFMA ----------
__global__ __launch_bounds__(256) void attn1_mfma_kernel(const unsigned short* __restrict__ ht,
                                                         const float* __restrict__ es,
                                                         const float* __restrict__ ed,
                                                         const float* __restrict__ adj,
                                                         const float* __restrict__ meanV1,
                                                         unsigned short* __restrict__ h1c,
                                                         const int* __restrict__ doc_p,
                                                         const int* __restrict__ sect_p,
                                                         int expert){
    __shared__ unsigned short aw[H][16][72];
    __shared__ float dsum[H][16][2];
    __shared__ float denomf[H][16];
    int tid = threadIdx.x, wave = tid >> 6, lane = tid & 63;
    int quad = lane >> 4, l16 = lane & 15;
    int s0 = blockIdx.x*16, b = blockIdx.y;
    int tlo = 0, thi = S;
    if (expert == 0) { thi = S - *sect_p - *doc_p; }
    else if (expert == 1) { tlo = S - *sect_p - *doc_p; thi = S - *doc_p; }
    else if (expert == 2) { tlo = S - *doc_p; }

    // weight-phase mapping (threads 0..191)
    int wh = tid >> 5, sub = tid & 31, wr = sub >> 1, th = sub & 1;
    float es_r = 0.f, dpart = 0.f;
    const float* adjrow = nullptr;
    const float* edrow = nullptr;
    if (tid < 192){
        es_r = es[((size_t)b*H + wh)*S + s0 + wr];
        adjrow = adj + ((size_t)(b*S + s0 + wr))*S;
        edrow = ed + ((size_t)b*H + wh)*S;
    }
    // MFMA frag pointers: head j, column tile = wave
    const unsigned short* bbase[H];
    #pragma unroll
    for (int j = 0; j < H; j++)
        bbase[j] = ht + ((size_t)b*HHD + j*64 + wave*16 + l16)*S;
    f32x4 zero = {0.f,0.f,0.f,0.f};
    f32x4 acc[H] = {zero, zero, zero, zero, zero, zero};

    for (int t0 = 0; t0 < S; t0 += 64){
        if (tid < 192){
            #pragma unroll
            for (int i = 0; i < 8; i++){
                int t = t0 + th*32 + i*4;
                float4 a4 = *(const float4*)(adjrow + t);
                float4 e4 = *(const float4*)(edrow + t);
                float av[4] = {a4.x,a4.y,a4.z,a4.w};
                float ev[4] = {e4.x,e4.y,e4.z,e4.w};
                #pragma unroll
                for (int j2 = 0; j2 < 4; j2++){
                    int tj = t + j2;
                    bool msk = (tj >= tlo) && (tj < thi) && (av[j2] > 0.f);
                    float w = msk ? __expf(leaky(es_r + ev[j2])) : 0.f;
                    dpart += w;
                    aw[wh][wr][th*32 + i*4 + j2] = f2bf(w);
                }
            }
        }
        __syncthreads();
        #pragma unroll
        for (int kk = 0; kk < 2; kk++){
            #pragma unroll
            for (int j = 0; j < H; j++){
                bf8_t a = *(const bf8_t*)(&aw[j][l16][kk*32 + quad*8]);
                bf8_t bv = *(const bf8_t*)(bbase[j] + t0 + kk*32 + quad*8);
                acc[j] = __builtin_amdgcn_mfma_f32_16x16x32_bf16(a, bv, acc[j], 0, 0, 0);
            }
        }
        __syncthreads();
    }
    if (tid < 192) dsum[wh][wr][th] = dpart;
    __syncthreads();
    if (tid < 96){
        int h2 = tid >> 4, r2 = tid & 15;
        denomf[h2][r2] = dsum[h2][r2][0] + dsum[h2][r2][1];
    }
    __syncthreads();
    #pragma unroll
    for (int j = 0; j < H; j++){
        int col = j*64 + wave*16 + l16;
        #pragma unroll
        for (int r = 0; r < 4; r++){
            int row = quad*4 + r;
            float dn = denomf[j][row];
            float v = (dn > 0.f) ? acc[j][r]/dn : meanV1[b*HHD + col];
            v = v > 0.f ? v : __expf(v) - 1.f;   // ELU
            h1c[((size_t)(b*S + s0 + row))*HHD + col] = f2bf(v);
        }
    }
}

// ---------- layer-2 attention, MFMA ----------
__global__ __launch_bounds__(256) void attn2_mfma_kernel(const unsigned short* __restrict__ h2t,
                                                         const float* __restrict__ f2s,
                                                         const float* __restrict__ f2d,
                                                         const float* __restrict__ adj,
                                                         const float* __restrict__ meanV2,
                                                         const float* __restrict__ rmask,
                                                         float* __restrict__ outp,
                                                         const int* __restrict__ doc_p,
                                                         const int* __restrict__ sect_p,
                                                         int expert, int accum){
    __shared__ unsigned short aw[16][72];
    __shared__ float dpart[16][16];
    __shared__ float denomf[16];
    int tid = threadIdx.x, wave = tid >> 6, lane = tid & 63;
    int quad = lane >> 4, l16 = lane & 15;
    int s0 = blockIdx.x*16, b = blockIdx.y;
    int tlo = 0, thi = S;
    if (expert == 0) { thi = S - *sect_p - *doc_p; }
    else if (expert == 1) { tlo = S - *sect_p - *doc_p; thi = S - *doc_p; }
    else if (expert == 2) { tlo = S - *doc_p; }

    int wr = tid >> 4, q = tid & 15;
    float fs_r = f2s[b*S + s0 + wr];
    const float* adjrow = adj + ((size_t)(b*S + s0 + wr))*S;
    const float* fdrow = f2d + (size_t)b*S;
    float dreg = 0.f;

    const unsigned short* bbase[4];
    #pragma unroll
    for (int j = 0; j < 4; j++)
        bbase[j] = h2t + ((size_t)b*D + (wave*4 + j)*16 + l16)*S;
    f32x4 zero = {0.f,0.f,0.f,0.f};
    f32x4 acc[4] = {zero, zero, zero, zero};

    for (int t0 = 0; t0 < S; t0 += 64){
        {
            int t = t0 + q*4;
            float4 a4 = *(const float4*)(adjrow + t);
            float4 e4 = *(const float4*)(fdrow + t);
            float av[4] = {a4.x,a4.y,a4.z,a4.w};
            float ev[4] = {e4.x,e4.y,e4.z,e4.w};
            #pragma unroll
            for (int j2 = 0; j2 < 4; j2++){
                int tj = t + j2;
                bool msk = (tj >= tlo) && (tj < thi) && (av[j2] > 0.f);
                float w = msk ? __expf(leaky(fs_r + ev[j2])) : 0.f;
                dreg += w;
                aw[wr][q*4 + j2] = f2bf(w);
            }
        }
        __syncthreads();
        #pragma unroll
        for (int kk = 0; kk < 2; kk++){
            bf8_t a = *(const bf8_t*)(&aw[l16][kk*32 + quad*8]);
            #pragma unroll
            for (int j = 0; j < 4; j++){
                bf8_t bv = *(const bf8_t*)(bbase[j] + t0 + kk*32 + quad*8);
                acc[j] = __builtin_amdgcn_mfma_f32_16x16x32_bf16(a, bv, acc[j], 0, 0, 0);
            }
        }
        __syncthreads();
    }
    dpart[wr][q] = dreg;
    __syncthreads();
    if (tid < 16){
        float s = 0.f;
        #pragma unroll
        for (int j = 0; j < 16; j++) s += dpart[tid][j];
        denomf[tid] = s;
    }
    __syncthreads();
    #pragma unroll
    for (int j = 0; j < 4; j++){
        int col = (wave*4 + j)*16 + l16;
        #pragma unroll
        for (int r = 0; r < 4; r++){
            int row = quad*4 + r;
            float dn = denomf[row];
            float v = (dn > 0.f) ? acc[j][r]/dn : meanV2[b*D + col];
            float* addr = outp + ((size_t)(b*S + s0 + row))*D + col;
            if (accum){
                float rm = rmask[b*S + s0 + row];
                *addr += rm*v;
            } else {
                *addr = v;
            }
        }
    }
}

// ---------- blend: MFMA GEMM + sigmoid + mix + mean ----------
__global__ __launch_bounds__(256) void blend_mfma_kernel(const unsigned short* __restrict__ featbf,
                                                         const unsigned short* __restrict__ bwt,
                                                         const float* __restrict__ bb,
                                                         const float* __restrict__ mainO,
                                                         const float* __restrict__ depO,
                                                         float* __restrict__ outp,
                                                         float* __restrict__ sumBuf){
    __shared__ float red[256];
    int tid = threadIdx.x, wave = tid >> 6, lane = tid & 63;
    int quad = lane >> 4, l16 = lane & 15;
    int m0 = blockIdx.x*64, n0 = blockIdx.y*64;   // m = row, n = col
    const unsigned short* arow = featbf + (size_t)(m0 + wave*16 + l16)*D + quad*8;
    const unsigned short* brow[4];
    #pragma unroll
    for (int j = 0; j < 4; j++)
        brow[j] = bwt + (size_t)(n0 + j*16 + l16)*D + quad*8;
    f32x4 zero = {0.f,0.f,0.f,0.f};
    f32x4 acc[4] = {zero, zero, zero, zero};
    for (int k0 = 0; k0 < D; k0 += 32){
        bf8_t a = *(const bf8_t*)(arow + k0);
        #pragma unroll
        for (int j = 0; j < 4; j++){
            bf8_t bv = *(const bf8_t*)(brow[j] + k0);
            acc[j] = __builtin_amdgcn_mfma_f32_16x16x32_bf16(a, bv, acc[j], 0, 0, 0);
        }
    }
    float lsum = 0.f;
    int mbase = m0 + wave*16 + quad*4;
    #pragma unroll
    for (int j = 0; j < 4; j++){
        int col = n0 + j*16 + l16;
        float bias = bb[col];
        #pragma unroll
        for (int r = 0; r < 4; r++){
            int row = mbase + r;
            size_t idx = (size_t)row*D + col;
            float bw = 1.f/(1.f + __expf(-(acc[j][r] + bias)));
            lsum += bw;
            outp[idx] = bw*mainO[idx] + (1.f - bw)*depO[idx];
        }
    }
    red[tid] = lsum;
    __syncthreads();
    for (int sft = 128; sft; sft >>= 1){
        if (tid < sft) red[tid] += red[tid + sft];
        __syncthreads();
    }
    if (tid == 0) atomicAdd(sumBuf, red[0]);
}

__global__ void finalize_kernel(const float* __restrict__ sumBuf, float* __restrict__ outp){
    float mc = *sumBuf / (float)(ROWS*D);
    outp[ROWS*D]     = fabsf(mc - 0.6f)*0.01f;
    outp[ROWS*D + 1] = mc;
}

extern "C" void kernel_launch(void* const* d_in, const int* in_sizes, int n_in,
                              void* d_out, int out_size, void* d_ws, size_t ws_size,
                              hipStream_t stream)
{
    const float* feature  = (const float*)d_in[0];
    const float* adj      = (const float*)d_in[1];
    const float* main_W1  = (const float*)d_in[2];
    const float* main_a1s = (const float*)d_in[3];
    const float* main_a1d = (const float*)d_in[4];
    const float* main_W2  = (const float*)d_in[5];
    const float* main_a2s = (const float*)d_in[6];
    const float* main_a2d = (const float*)d_in[7];
    const float* dep_W1   = (const float*)d_in[8];
    const float* dep_a1s  = (const float*)d_in[9];
    const float* dep_a1d  = (const float*)d_in[10];
    const float* dep_W2   = (const float*)d_in[11];
    const float* dep_a2s  = (const float*)d_in[12];
    const float* dep_a2d  = (const float*)d_in[13];
    const float* router_W = (const float*)d_in[14];
    const float* blend_W  = (const float*)d_in[15];
    const float* blend_b  = (const float*)d_in[16];
    const int*   doc_p    = (const int*)d_in[17];
    const int*   sect_p   = (const int*)d_in[18];

    char* ws = (char*)d_ws;
    size_t off = 0;
    unsigned short* featbf = (unsigned short*)(ws + off); off += (size_t)ROWS*D*2;
    unsigned short* w1nk   = (unsigned short*)(ws + off); off += (size_t)4*HHD*D*2;
    unsigned short* w2nk   = (unsigned short*)(ws + off); off += (size_t)4*D*HHD*2;
    unsigned short* bwt    = (unsigned short*)(ws + off); off += (size_t)D*D*2;
    unsigned short* ht     = (unsigned short*)(ws + off); off += (size_t)B*HHD*S*2;
    unsigned short* h1c    = (unsigned short*)(ws + off); off += (size_t)ROWS*HHD*2;
    unsigned short* h2t    = (unsigned short*)(ws + off); off += (size_t)B*D*S*2;
    float* esb    = (float*)(ws + off); off += (size_t)B*H*S*4;
    float* edb    = (float*)(ws + off); off += (size_t)B*H*S*4;
    float* f2sb   = (float*)(ws + off); off += (size_t)ROWS*4;
    float* f2db   = (float*)(ws + off); off += (size_t)ROWS*4;
    float* meanV1 = (float*)(ws + off); off += (size_t)B*HHD*4;
    float* meanV2 = (float*)(ws + off); off += (size_t)B*D*4;
    float* rmask  = (float*)(ws + off); off += (size_t)NE*ROWS*4;
    float* mainO  = (float*)(ws + off); off += (size_t)ROWS*D*4;
    float* depO   = (float*)(ws + off); off += (size_t)ROWS*D*4;
    float* sumBuf = (float*)(ws + off); off += 16;
    float* outp   = (float*)d_out;

    conv_feat_kernel<<<ROWS*D/4/256, 256, 0, stream>>>(feature, featbf);
    prep_w1_kernel<<<dim3(HHD*D/256, 4), 256, 0, stream>>>(main_W1, dep_W1, w1nk);
    prep_w2_kernel<<<dim3(D, 4), HHD, 0, stream>>>(main_W2, dep_W2, w2nk);
    prep_bw_kernel<<<D, D, 0, stream>>>(blend_W, bwt);
    zero_kernel<<<ROWS*D/4/256, 256, 0, stream>>>(depO, sumBuf);
    router_kernel<<<ROWS/4, 256, 0, stream>>>(feature, router_W, rmask);

    for (int e = -1; e < NE; e++){
        int ei = e + 1;   // 0 = main, 1..3 = deputies
        const float* rs = (e < 0) ? nullptr : (rmask + (size_t)e*ROWS);
        const float* a1s = (e < 0) ? main_a1s : dep_a1s + (size_t)e*H*HD;
        const float* a1d = (e < 0) ? main_a1d : dep_a1d + (size_t)e*H*HD;
        const float* a2s = (e < 0) ? main_a2s : dep_a2s + (size_t)e*D;
        const float* a2d = (e < 0) ? main_a2d : dep_a2d + (size_t)e*D;

        gemm_tn_kernel<D, HHD><<<dim3(HHD/64, ROWS/64), 256, 0, stream>>>(
            w1nk + (size_t)ei*HHD*D, featbf, rs, ht);
        esed_kernel<<<dim3(B*H, S/256), 256, 0, stream>>>(ht, a1s, a1d, esb, edb);
        colmean_kernel<<<B*HHD/4, 256, 0, stream>>>(ht, meanV1);
        attn1_mfma_kernel<<<dim3(S/16, B), 256, 0, stream>>>(ht, esb, edb, adj, meanV1,
                                                             h1c, doc_p, sect_p, e);
        gemm_tn_kernel<HHD, D><<<dim3(D/64, ROWS/64), 256, 0, stream>>>(
            w2nk + (size_t)ei*D*HHD, h1c, nullptr, h2t);
        f2dots_kernel<<<dim3(B, S/256), 256, 0, stream>>>(h2t, a2s, a2d, f2sb, f2db);
        colmean_kernel<<<B*D/4, 256, 0, stream>>>(h2t, meanV2);
        attn2_mfma_kernel<<<dim3(S/16, B), 256, 0, stream>>>(
            h2t, f2sb, f2db, adj, meanV2,
            (e < 0) ? nullptr : rmask + (size_t)e*ROWS,
            (e < 0) ? mainO : depO,
            doc_p, sect_p, e, (e < 0) ? 0 : 1);
    }

    blend_mfma_kernel<<<dim3(ROWS/64, D/64), 256, 0, stream>>>(featbf, bwt, blend_b,
                                                               mainO, depO, outp, sumBuf);
    finalize_kernel<<<1, 1, 0, stream>>>(sumBuf, outp);
}

// Round 3
// 424.303 us; speedup vs baseline: 3.7294x; 1.9218x over previous
//
#include <hip/hip_runtime.h>
#include <math.h>

#define B 4
#define S 1024
#define D 256
#define H 6
#define HD 64
#define NE 3
#define HHD 384
#define ROWS (B*S)

typedef __attribute__((ext_vector_type(8))) short bf8_t;
typedef __attribute__((ext_vector_type(4))) float f32x4;

__device__ __forceinline__ float leaky(float x){ return x > 0.f ? x : 0.2f*x; }

__device__ __forceinline__ unsigned short f2bf(float f){
    union { float f; unsigned int u; } v; v.f = f;
    unsigned int u = v.u;
    return (unsigned short)((u + 0x7FFFu + ((u >> 16) & 1u)) >> 16);
}
__device__ __forceinline__ float bf2f(unsigned short h){
    union { unsigned int u; float f; } v; v.u = ((unsigned int)h) << 16;
    return v.f;
}

// ---------- prep ----------
__global__ __launch_bounds__(256) void conv_feat_kernel(const float* __restrict__ src,
                                                        unsigned short* __restrict__ dst){
    int idx = blockIdx.x*256 + threadIdx.x;             // < ROWS*D/4
    float4 v = ((const float4*)src)[idx];
    ushort4 o;
    o.x = f2bf(v.x); o.y = f2bf(v.y); o.z = f2bf(v.z); o.w = f2bf(v.w);
    ((ushort4*)dst)[idx] = o;
}

__global__ __launch_bounds__(256) void conv_adj_kernel(const float* __restrict__ adj,
                                                       unsigned char* __restrict__ adjm){
    int idx = blockIdx.x*256 + threadIdx.x;             // < B*S*S/4
    float4 v = ((const float4*)adj)[idx];
    uchar4 o;
    o.x = v.x > 0.f; o.y = v.y > 0.f; o.z = v.z > 0.f; o.w = v.w > 0.f;
    ((uchar4*)adjm)[idx] = o;
}

// w1nk[e][n=h*64+o][k=f] = W1_e[h][f][o]
__global__ __launch_bounds__(256) void prep_w1_kernel(const float* __restrict__ mainW,
                                                      const float* __restrict__ depW,
                                                      unsigned short* __restrict__ dst){
    int e = blockIdx.y;
    const float* src = (e == 0) ? mainW : depW + (size_t)(e-1)*H*D*HD;
    int idx = blockIdx.x*256 + threadIdx.x;             // < HHD*D
    int n = idx >> 8, k = idx & 255;
    int h = n >> 6, o = n & 63;
    dst[(size_t)e*HHD*D + idx] = f2bf(src[(h*D + k)*HD + o]);
}

// w2nk[e][n=d][k] = W2_e[k][d]
__global__ __launch_bounds__(384) void prep_w2_kernel(const float* __restrict__ mainW,
                                                      const float* __restrict__ depW,
                                                      unsigned short* __restrict__ dst){
    int e = blockIdx.y;
    const float* src = (e == 0) ? mainW : depW + (size_t)(e-1)*HHD*D;
    int k = threadIdx.x, n = blockIdx.x;
    dst[((size_t)e*D + n)*HHD + k] = f2bf(src[k*D + n]);
}

__global__ __launch_bounds__(256) void prep_bw_kernel(const float* __restrict__ src,
                                                      unsigned short* __restrict__ dst){
    int k = threadIdx.x, col = blockIdx.x;
    dst[col*D + k] = f2bf(src[k*D + col]);
}

__global__ __launch_bounds__(256) void zero_kernel(float* __restrict__ p, int n){
    int idx = blockIdx.x*256 + threadIdx.x;
    if (idx < n) p[idx] = 0.f;
}

__global__ __launch_bounds__(256) void router_kernel(const float* __restrict__ x,
                                                     const float* __restrict__ rw,
                                                     float* __restrict__ rmask){
    int wave = threadIdx.x >> 6, lane = threadIdx.x & 63;
    int row = blockIdx.x*4 + wave;
    float4 xv = ((const float4*)(x + (size_t)row*D))[lane];
    int f = lane*4;
    float xa[4] = {xv.x, xv.y, xv.z, xv.w};
    float p0 = 0.f, p1 = 0.f, p2 = 0.f;
    #pragma unroll
    for (int j = 0; j < 4; j++){
        p0 += xa[j]*rw[(f+j)*NE + 0];
        p1 += xa[j]*rw[(f+j)*NE + 1];
        p2 += xa[j]*rw[(f+j)*NE + 2];
    }
    for (int off = 32; off; off >>= 1){
        p0 += __shfl_down(p0, off);
        p1 += __shfl_down(p1, off);
        p2 += __shfl_down(p2, off);
    }
    if (lane == 0){
        float p[3] = {p0, p1, p2};
        int ex = 0;
        for (int e = 1; e < NE; e++) if (p[e] <= p[ex]) ex = e;
        for (int e = 0; e < NE; e++) rmask[e*ROWS + row] = (e == ex) ? 0.f : 1.f;
    }
}

// ---------- GEMM1 (x@W1, transposed out) + fused es/ed + colmean ----------
// grid (HHD/64=H, ROWS/64, 4experts)
__global__ __launch_bounds__(256) void gemm1_kernel(const unsigned short* __restrict__ w1nk,
                                                    const unsigned short* __restrict__ featbf,
                                                    const float* __restrict__ rmask,
                                                    const float* __restrict__ main_a1s,
                                                    const float* __restrict__ main_a1d,
                                                    const float* __restrict__ dep_a1s,
                                                    const float* __restrict__ dep_a1d,
                                                    unsigned short* __restrict__ ht4,
                                                    float* __restrict__ es4,
                                                    float* __restrict__ ed4,
                                                    float* __restrict__ meanV1){
    __shared__ float ep[2][64][17];
    int tid = threadIdx.x, wave = tid >> 6, lane = tid & 63;
    int quad = lane >> 4, l16 = lane & 15;
    int e = blockIdx.z;
    int m0 = blockIdx.x*64;         // head h = blockIdx.x
    int n0 = blockIdx.y*64;
    const unsigned short* arow = w1nk + (size_t)e*HHD*D + (size_t)(m0 + wave*16 + l16)*D + quad*8;
    const unsigned short* brow[4];
    bool zr[4];
    #pragma unroll
    for (int j = 0; j < 4; j++){
        int n = n0 + j*16 + l16;
        brow[j] = featbf + (size_t)n*D + quad*8;
        zr[j] = (e > 0) ? (rmask[(size_t)(e-1)*ROWS + n] == 0.f) : false;
    }
    f32x4 z4 = {0.f,0.f,0.f,0.f};
    f32x4 acc[4] = {z4, z4, z4, z4};
    bf8_t bz = {0,0,0,0,0,0,0,0};
    for (int k0 = 0; k0 < D; k0 += 32){
        bf8_t a = *(const bf8_t*)(arow + k0);
        #pragma unroll
        for (int j = 0; j < 4; j++){
            bf8_t bv = zr[j] ? bz : *(const bf8_t*)(brow[j] + k0);
            acc[j] = __builtin_amdgcn_mfma_f32_16x16x32_bf16(a, bv, acc[j], 0, 0, 0);
        }
    }
    int b = n0 >> 10;
    int mbase = m0 + wave*16 + quad*4;
    unsigned short* htb = ht4 + (size_t)e*B*HHD*S;
    #pragma unroll
    for (int j = 0; j < 4; j++){
        int s = (n0 + j*16 + l16) & 1023;
        #pragma unroll
        for (int r = 0; r < 4; r++)
            htb[((size_t)b*HHD + mbase + r)*S + s] = f2bf(acc[j][r]);
    }
    const float* a1sp = (e == 0) ? main_a1s : dep_a1s + (size_t)(e-1)*H*HD;
    const float* a1dp = (e == 0) ? main_a1d : dep_a1d + (size_t)(e-1)*H*HD;
    float a1sv[4], a1dv[4];
    #pragma unroll
    for (int r = 0; r < 4; r++){ a1sv[r] = a1sp[mbase + r]; a1dv[r] = a1dp[mbase + r]; }
    #pragma unroll
    for (int j = 0; j < 4; j++){
        float ps = 0.f, pd = 0.f;
        #pragma unroll
        for (int r = 0; r < 4; r++){ ps += acc[j][r]*a1sv[r]; pd += acc[j][r]*a1dv[r]; }
        ep[0][j*16 + l16][wave*4 + quad] = ps;
        ep[1][j*16 + l16][wave*4 + quad] = pd;
    }
    #pragma unroll
    for (int r = 0; r < 4; r++){
        float cm = acc[0][r] + acc[1][r] + acc[2][r] + acc[3][r];
        for (int off = 8; off; off >>= 1) cm += __shfl_down(cm, off, 16);
        if (l16 == 0)
            atomicAdd(meanV1 + ((size_t)e*B + b)*HHD + mbase + r, cm*(1.f/(float)S));
    }
    __syncthreads();
    if (tid < 128){
        int arr = tid >> 6, s = tid & 63;
        float sum = 0.f;
        #pragma unroll
        for (int i = 0; i < 16; i++) sum += ep[arr][s][i];
        int n = n0 + s;
        float* dst = arr ? ed4 : es4;
        dst[(((size_t)e*B + (n >> 10))*H + blockIdx.x)*S + (n & 1023)] = sum;
    }
}

// ---------- GEMM2 (h1@W2, transposed out) + fused f2s/f2d + colmean ----------
// grid (D/64=4, ROWS/64, 4experts)
__global__ __launch_bounds__(256) void gemm2_kernel(const unsigned short* __restrict__ w2nk,
                                                    const unsigned short* __restrict__ h1c4,
                                                    const float* __restrict__ main_a2s,
                                                    const float* __restrict__ main_a2d,
                                                    const float* __restrict__ dep_a2s,
                                                    const float* __restrict__ dep_a2d,
                                                    unsigned short* __restrict__ h2t4,
                                                    float* __restrict__ f2s4,
                                                    float* __restrict__ f2d4,
                                                    float* __restrict__ meanV2){
    __shared__ float ep[2][64][17];
    int tid = threadIdx.x, wave = tid >> 6, lane = tid & 63;
    int quad = lane >> 4, l16 = lane & 15;
    int e = blockIdx.z;
    int m0 = blockIdx.x*64;
    int n0 = blockIdx.y*64;
    const unsigned short* arow = w2nk + (size_t)e*D*HHD + (size_t)(m0 + wave*16 + l16)*HHD + quad*8;
    const unsigned short* brow[4];
    #pragma unroll
    for (int j = 0; j < 4; j++)
        brow[j] = h1c4 + (size_t)e*ROWS*HHD + (size_t)(n0 + j*16 + l16)*HHD + quad*8;
    f32x4 z4 = {0.f,0.f,0.f,0.f};
    f32x4 acc[4] = {z4, z4, z4, z4};
    for (int k0 = 0; k0 < HHD; k0 += 32){
        bf8_t a = *(const bf8_t*)(arow + k0);
        #pragma unroll
        for (int j = 0; j < 4; j++){
            bf8_t bv = *(const bf8_t*)(brow[j] + k0);
            acc[j] = __builtin_amdgcn_mfma_f32_16x16x32_bf16(a, bv, acc[j], 0, 0, 0);
        }
    }
    int b = n0 >> 10;
    int mbase = m0 + wave*16 + quad*4;
    unsigned short* h2b = h2t4 + (size_t)e*B*D*S;
    #pragma unroll
    for (int j = 0; j < 4; j++){
        int s = (n0 + j*16 + l16) & 1023;
        #pragma unroll
        for (int r = 0; r < 4; r++)
            h2b[((size_t)b*D + mbase + r)*S + s] = f2bf(acc[j][r]);
    }
    const float* a2sp = (e == 0) ? main_a2s : dep_a2s + (size_t)(e-1)*D;
    const float* a2dp = (e == 0) ? main_a2d : dep_a2d + (size_t)(e-1)*D;
    float a2sv[4], a2dv[4];
    #pragma unroll
    for (int r = 0; r < 4; r++){ a2sv[r] = a2sp[mbase + r]; a2dv[r] = a2dp[mbase + r]; }
    #pragma unroll
    for (int j = 0; j < 4; j++){
        float ps = 0.f, pd = 0.f;
        #pragma unroll
        for (int r = 0; r < 4; r++){ ps += acc[j][r]*a2sv[r]; pd += acc[j][r]*a2dv[r]; }
        ep[0][j*16 + l16][wave*4 + quad] = ps;
        ep[1][j*16 + l16][wave*4 + quad] = pd;
    }
    #pragma unroll
    for (int r = 0; r < 4; r++){
        float cm = acc[0][r] + acc[1][r] + acc[2][r] + acc[3][r];
        for (int off = 8; off; off >>= 1) cm += __shfl_down(cm, off, 16);
        if (l16 == 0)
            atomicAdd(meanV2 + ((size_t)e*B + b)*D + mbase + r, cm*(1.f/(float)S));
    }
    __syncthreads();
    if (tid < 128){
        int arr = tid >> 6, s = tid & 63;
        float sum = 0.f;
        #pragma unroll
        for (int i = 0; i < 16; i++) sum += ep[arr][s][i];
        int n = n0 + s;
        float* dst = arr ? f2d4 : f2s4;
        atomicAdd(dst + (size_t)e*ROWS + n, sum);
    }
}

// ---------- attn1: one head per block ----------
// grid (S/16, H, 4experts*B)
__global__ __launch_bounds__(256) void attn1_kernel(const unsigned short* __restrict__ ht4,
                                                    const float* __restrict__ es4,
                                                    const float* __restrict__ ed4,
                                                    const unsigned char* __restrict__ adjm,
                                                    const float* __restrict__ meanV1,
                                                    unsigned short* __restrict__ h1c4,
                                                    const int* __restrict__ doc_p,
                                                    const int* __restrict__ sect_p){
    __shared__ unsigned short aw[16][72];
    __shared__ float dpart[16][17];
    __shared__ float denom[16];
    int tid = threadIdx.x, wave = tid >> 6, lane = tid & 63;
    int quad = lane >> 4, l16 = lane & 15;
    int s0 = blockIdx.x*16, h = blockIdx.y;
    int e = blockIdx.z >> 2, b = blockIdx.z & 3;
    int tlo = 0, thi = S;
    int ex = e - 1;
    if (ex == 0){ thi = S - *sect_p - *doc_p; }
    else if (ex == 1){ tlo = S - *sect_p - *doc_p; thi = S - *doc_p; }
    else if (ex == 2){ tlo = S - *doc_p; }
    int wr = tid >> 4, q = tid & 15;
    float es_r = es4[(((size_t)e*B + b)*H + h)*S + s0 + wr];
    const unsigned char* adjrow = adjm + ((size_t)(b*S + s0 + wr))*S;
    const float* edrow = ed4 + (((size_t)e*B + b)*H + h)*S;
    const unsigned short* bbase = ht4 + (((size_t)e*B + b)*HHD + h*64 + wave*16 + l16)*S;
    f32x4 acc = {0.f,0.f,0.f,0.f};
    float dreg = 0.f;
    for (int t0 = 0; t0 < S; t0 += 64){
        int t = t0 + q*4;
        uchar4 am = *(const uchar4*)(adjrow + t);
        float4 ev = *(const float4*)(edrow + t);
        unsigned char av[4] = {am.x, am.y, am.z, am.w};
        float e4[4] = {ev.x, ev.y, ev.z, ev.w};
        #pragma unroll
        for (int j = 0; j < 4; j++){
            int tj = t + j;
            bool msk = (tj >= tlo) && (tj < thi) && (av[j] != 0);
            float w = msk ? __expf(leaky(es_r + e4[j])) : 0.f;
            dreg += w;
            aw[wr][q*4 + j] = f2bf(w);
        }
        __syncthreads();
        #pragma unroll
        for (int kk = 0; kk < 2; kk++){
            bf8_t a = *(const bf8_t*)(&aw[l16][kk*32 + quad*8]);
            bf8_t bv = *(const bf8_t*)(bbase + t0 + kk*32 + quad*8);
            acc = __builtin_amdgcn_mfma_f32_16x16x32_bf16(a, bv, acc, 0, 0, 0);
        }
        __syncthreads();
    }
    dpart[wr][q] = dreg;
    __syncthreads();
    if (tid < 16){
        float s = 0.f;
        #pragma unroll
        for (int j = 0; j < 16; j++) s += dpart[tid][j];
        denom[tid] = s;
    }
    __syncthreads();
    int col = h*64 + wave*16 + l16;
    #pragma unroll
    for (int r = 0; r < 4; r++){
        int row = quad*4 + r;
        float dn = denom[row];
        float v = (dn > 0.f) ? acc[r]/dn : meanV1[((size_t)e*B + b)*HHD + col];
        v = v > 0.f ? v : __expf(v) - 1.f;   // ELU
        h1c4[(size_t)e*ROWS*HHD + ((size_t)(b*S + s0 + row))*HHD + col] = f2bf(v);
    }
}

// ---------- attn2: 64-col tile per block ----------
// grid (S/16, D/64, 4experts*B)
__global__ __launch_bounds__(256) void attn2_kernel(const unsigned short* __restrict__ h2t4,
                                                    const float* __restrict__ f2s4,
                                                    const float* __restrict__ f2d4,
                                                    const unsigned char* __restrict__ adjm,
                                                    const float* __restrict__ meanV2,
                                                    float* __restrict__ mainO,
                                                    unsigned short* __restrict__ depO3,
                                                    const int* __restrict__ doc_p,
                                                    const int* __restrict__ sect_p){
    __shared__ unsigned short aw[16][72];
    __shared__ float dpart[16][17];
    __shared__ float denom[16];
    int tid = threadIdx.x, wave = tid >> 6, lane = tid & 63;
    int quad = lane >> 4, l16 = lane & 15;
    int s0 = blockIdx.x*16, n0 = blockIdx.y*64;
    int e = blockIdx.z >> 2, b = blockIdx.z & 3;
    int tlo = 0, thi = S;
    int ex = e - 1;
    if (ex == 0){ thi = S - *sect_p - *doc_p; }
    else if (ex == 1){ tlo = S - *sect_p - *doc_p; thi = S - *doc_p; }
    else if (ex == 2){ tlo = S - *doc_p; }
    int wr = tid >> 4, q = tid & 15;
    float fs_r = f2s4[(size_t)e*ROWS + b*S + s0 + wr];
    const unsigned char* adjrow = adjm + ((size_t)(b*S + s0 + wr))*S;
    const float* fdrow = f2d4 + (size_t)e*ROWS + b*S;
    const unsigned short* bbase = h2t4 + (((size_t)e*B + b)*D + n0 + wave*16 + l16)*S;
    f32x4 acc = {0.f,0.f,0.f,0.f};
    float dreg = 0.f;
    for (int t0 = 0; t0 < S; t0 += 64){
        int t = t0 + q*4;
        uchar4 am = *(const uchar4*)(adjrow + t);
        float4 ev = *(const float4*)(fdrow + t);
        unsigned char av[4] = {am.x, am.y, am.z, am.w};
        float e4[4] = {ev.x, ev.y, ev.z, ev.w};
        #pragma unroll
        for (int j = 0; j < 4; j++){
            int tj = t + j;
            bool msk = (tj >= tlo) && (tj < thi) && (av[j] != 0);
            float w = msk ? __expf(leaky(fs_r + e4[j])) : 0.f;
            dreg += w;
            aw[wr][q*4 + j] = f2bf(w);
        }
        __syncthreads();
        #pragma unroll
        for (int kk = 0; kk < 2; kk++){
            bf8_t a = *(const bf8_t*)(&aw[l16][kk*32 + quad*8]);
            bf8_t bv = *(const bf8_t*)(bbase + t0 + kk*32 + quad*8);
            acc = __builtin_amdgcn_mfma_f32_16x16x32_bf16(a, bv, acc, 0, 0, 0);
        }
        __syncthreads();
    }
    dpart[wr][q] = dreg;
    __syncthreads();
    if (tid < 16){
        float s = 0.f;
        #pragma unroll
        for (int j = 0; j < 16; j++) s += dpart[tid][j];
        denom[tid] = s;
    }
    __syncthreads();
    int col = n0 + wave*16 + l16;
    #pragma unroll
    for (int r = 0; r < 4; r++){
        int row = quad*4 + r;
        float dn = denom[row];
        float v = (dn > 0.f) ? acc[r]/dn : meanV2[((size_t)e*B + b)*D + col];
        size_t idx = ((size_t)(b*S + s0 + row))*D + col;
        if (e == 0) mainO[idx] = v;
        else        depO3[(size_t)(e-1)*ROWS*D + idx] = f2bf(v);
    }
}

// ---------- blend ----------
__global__ __launch_bounds__(256) void blend_mfma_kernel(const unsigned short* __restrict__ featbf,
                                                         const unsigned short* __restrict__ bwt,
                                                         const float* __restrict__ bb,
                                                         const float* __restrict__ mainO,
                                                         const unsigned short* __restrict__ depO3,
                                                         const float* __restrict__ rmask,
                                                         float* __restrict__ outp,
                                                         float* __restrict__ sumBuf){
    __shared__ float red[256];
    int tid = threadIdx.x, wave = tid >> 6, lane = tid & 63;
    int quad = lane >> 4, l16 = lane & 15;
    int m0 = blockIdx.x*64, n0 = blockIdx.y*64;
    const unsigned short* arow = featbf + (size_t)(m0 + wave*16 + l16)*D + quad*8;
    const unsigned short* brow[4];
    #pragma unroll
    for (int j = 0; j < 4; j++)
        brow[j] = bwt + (size_t)(n0 + j*16 + l16)*D + quad*8;
    f32x4 z4 = {0.f,0.f,0.f,0.f};
    f32x4 acc[4] = {z4, z4, z4, z4};
    for (int k0 = 0; k0 < D; k0 += 32){
        bf8_t a = *(const bf8_t*)(arow + k0);
        #pragma unroll
        for (int j = 0; j < 4; j++){
            bf8_t bv = *(const bf8_t*)(brow[j] + k0);
            acc[j] = __builtin_amdgcn_mfma_f32_16x16x32_bf16(a, bv, acc[j], 0, 0, 0);
        }
    }
    float lsum = 0.f;
    int mbase = m0 + wave*16 + quad*4;
    float rm[4][3];
    #pragma unroll
    for (int r = 0; r < 4; r++)
        #pragma unroll
        for (int e0 = 0; e0 < 3; e0++)
            rm[r][e0] = rmask[(size_t)e0*ROWS + mbase + r];
    #pragma unroll
    for (int j = 0; j < 4; j++){
        int col = n0 + j*16 + l16;
        float bias = bb[col];
        #pragma unroll
        for (int r = 0; r < 4; r++){
            size_t idx = (size_t)(mbase + r)*D + col;
            float dep = 0.f;
            #pragma unroll
            for (int e0 = 0; e0 < 3; e0++)
                dep += rm[r][e0]*bf2f(depO3[(size_t)e0*ROWS*D + idx]);
            float bw = 1.f/(1.f + __expf(-(acc[j][r] + bias)));
            lsum += bw;
            outp[idx] = bw*mainO[idx] + (1.f - bw)*dep;
        }
    }
    red[tid] = lsum;
    __syncthreads();
    for (int sft = 128; sft; sft >>= 1){
        if (tid < sft) red[tid] += red[tid + sft];
        __syncthreads();
    }
    if (tid == 0) atomicAdd(sumBuf, red[0]);
}

__global__ void finalize_kernel(const float* __restrict__ sumBuf, float* __restrict__ outp){
    float mc = *sumBuf / (float)(ROWS*D);
    outp[ROWS*D]     = fabsf(mc - 0.6f)*0.01f;
    outp[ROWS*D + 1] = mc;
}

extern "C" void kernel_launch(void* const* d_in, const int* in_sizes, int n_in,
                              void* d_out, int out_size, void* d_ws, size_t ws_size,
                              hipStream_t stream)
{
    const float* feature  = (const float*)d_in[0];
    const float* adj      = (const float*)d_in[1];
    const float* main_W1  = (const float*)d_in[2];
    const float* main_a1s = (const float*)d_in[3];
    const float* main_a1d = (const float*)d_in[4];
    const float* main_W2  = (const float*)d_in[5];
    const float* main_a2s = (const float*)d_in[6];
    const float* main_a2d = (const float*)d_in[7];
    const float* dep_W1   = (const float*)d_in[8];
    const float* dep_a1s  = (const float*)d_in[9];
    const float* dep_a1d  = (const float*)d_in[10];
    const float* dep_W2   = (const float*)d_in[11];
    const float* dep_a2s  = (const float*)d_in[12];
    const float* dep_a2d  = (const float*)d_in[13];
    const float* router_W = (const float*)d_in[14];
    const float* blend_W  = (const float*)d_in[15];
    const float* blend_b  = (const float*)d_in[16];
    const int*   doc_p    = (const int*)d_in[17];
    const int*   sect_p   = (const int*)d_in[18];

    char* ws = (char*)d_ws;
    size_t off = 0;
    unsigned short* featbf = (unsigned short*)(ws + off); off += (size_t)ROWS*D*2;       // 2 MB
    unsigned char*  adjm   = (unsigned char*)(ws + off);  off += (size_t)B*S*S;          // 4 MB
    unsigned short* w1nk   = (unsigned short*)(ws + off); off += (size_t)4*HHD*D*2;
    unsigned short* w2nk   = (unsigned short*)(ws + off); off += (size_t)4*D*HHD*2;
    unsigned short* bwt    = (unsigned short*)(ws + off); off += (size_t)D*D*2;
    unsigned short* ht4    = (unsigned short*)(ws + off); off += (size_t)4*B*HHD*S*2;    // 12 MB
    unsigned short* h2t4   = ht4;                          // alias: ht dead before gemm2 writes
    unsigned short* h1c4   = (unsigned short*)(ws + off); off += (size_t)4*ROWS*HHD*2;   // 12 MB
    float* mainO  = (float*)h1c4;                          // alias: h1c dead before attn2 writes
    unsigned short* depO3 = (unsigned short*)((char*)h1c4 + (size_t)ROWS*D*4);
    float* es4    = (float*)(ws + off); off += (size_t)4*B*H*S*4;
    float* ed4    = (float*)(ws + off); off += (size_t)4*B*H*S*4;
    // contiguous zero region:
    float* f2s4   = (float*)(ws + off); off += (size_t)4*ROWS*4;
    float* f2d4   = (float*)(ws + off); off += (size_t)4*ROWS*4;
    float* meanV1 = (float*)(ws + off); off += (size_t)4*B*HHD*4;
    float* meanV2 = (float*)(ws + off); off += (size_t)4*B*D*4;
    float* sumBuf = (float*)(ws + off); off += 64;
    const int nzero = 4*ROWS + 4*ROWS + 4*B*HHD + 4*B*D + 16;
    float* rmask  = (float*)(ws + off); off += (size_t)NE*ROWS*4;
    float* outp   = (float*)d_out;

    conv_feat_kernel<<<ROWS*D/4/256, 256, 0, stream>>>(feature, featbf);
    conv_adj_kernel<<<B*S*S/4/256, 256, 0, stream>>>(adj, adjm);
    prep_w1_kernel<<<dim3(HHD*D/256, 4), 256, 0, stream>>>(main_W1, dep_W1, w1nk);
    prep_w2_kernel<<<dim3(D, 4), HHD, 0, stream>>>(main_W2, dep_W2, w2nk);
    prep_bw_kernel<<<D, D, 0, stream>>>(blend_W, bwt);
    zero_kernel<<<(nzero + 255)/256, 256, 0, stream>>>(f2s4, nzero);
    router_kernel<<<ROWS/4, 256, 0, stream>>>(feature, router_W, rmask);

    gemm1_kernel<<<dim3(H, ROWS/64, 4), 256, 0, stream>>>(w1nk, featbf, rmask,
        main_a1s, main_a1d, dep_a1s, dep_a1d, ht4, es4, ed4, meanV1);
    attn1_kernel<<<dim3(S/16, H, 4*B), 256, 0, stream>>>(ht4, es4, ed4, adjm, meanV1,
        h1c4, doc_p, sect_p);
    gemm2_kernel<<<dim3(D/64, ROWS/64, 4), 256, 0, stream>>>(w2nk, h1c4,
        main_a2s, main_a2d, dep_a2s, dep_a2d, h2t4, f2s4, f2d4, meanV2);
    attn2_kernel<<<dim3(S/16, D/64, 4*B), 256, 0, stream>>>(h2t4, f2s4, f2d4, adjm, meanV2,
        mainO, depO3, doc_p, sect_p);

    blend_mfma_kernel<<<dim3(ROWS/64, D/64), 256, 0, stream>>>(featbf, bwt, blend_b,
        mainO, depO3, rmask, outp, sumBuf);
    finalize_kernel<<<1, 1, 0, stream>>>(sumBuf, outp);
}

// Round 4
// 322.027 us; speedup vs baseline: 4.9138x; 1.3176x over previous
//
#include <hip/hip_runtime.h>
#include <math.h>

#define B 4
#define S 1024
#define D 256
#define H 6
#define HD 64
#define NE 3
#define HHD 384
#define ROWS (B*S)

typedef __attribute__((ext_vector_type(8))) short bf8_t;
typedef __attribute__((ext_vector_type(4))) float f32x4;

__device__ __forceinline__ float leaky(float x){ return x > 0.f ? x : 0.2f*x; }

__device__ __forceinline__ unsigned short f2bf(float f){
    union { float f; unsigned int u; } v; v.f = f;
    unsigned int u = v.u;
    return (unsigned short)((u + 0x7FFFu + ((u >> 16) & 1u)) >> 16);
}
__device__ __forceinline__ float bf2f(unsigned short h){
    union { unsigned int u; float f; } v; v.u = ((unsigned int)h) << 16;
    return v.f;
}

// ---------- prep ----------
__global__ __launch_bounds__(256) void conv_feat_kernel(const float* __restrict__ src,
                                                        unsigned short* __restrict__ dst){
    int idx = blockIdx.x*256 + threadIdx.x;             // < ROWS*D/4
    float4 v = ((const float4*)src)[idx];
    ushort4 o;
    o.x = f2bf(v.x); o.y = f2bf(v.y); o.z = f2bf(v.z); o.w = f2bf(v.w);
    ((ushort4*)dst)[idx] = o;
}

__global__ __launch_bounds__(256) void conv_adj_kernel(const float* __restrict__ adj,
                                                       unsigned char* __restrict__ adjm){
    int idx = blockIdx.x*256 + threadIdx.x;             // < B*S*S/4
    float4 v = ((const float4*)adj)[idx];
    uchar4 o;
    o.x = v.x > 0.f; o.y = v.y > 0.f; o.z = v.z > 0.f; o.w = v.w > 0.f;
    ((uchar4*)adjm)[idx] = o;
}

// w1nk[e][n=h*64+o][k=f] = W1_e[h][f][o]
__global__ __launch_bounds__(256) void prep_w1_kernel(const float* __restrict__ mainW,
                                                      const float* __restrict__ depW,
                                                      unsigned short* __restrict__ dst){
    int e = blockIdx.y;
    const float* src = (e == 0) ? mainW : depW + (size_t)(e-1)*H*D*HD;
    int idx = blockIdx.x*256 + threadIdx.x;             // < HHD*D
    int n = idx >> 8, k = idx & 255;
    int h = n >> 6, o = n & 63;
    dst[(size_t)e*HHD*D + idx] = f2bf(src[(h*D + k)*HD + o]);
}

// w2nk[e][n=d][k] = W2_e[k][d]
__global__ __launch_bounds__(384) void prep_w2_kernel(const float* __restrict__ mainW,
                                                      const float* __restrict__ depW,
                                                      unsigned short* __restrict__ dst){
    int e = blockIdx.y;
    const float* src = (e == 0) ? mainW : depW + (size_t)(e-1)*HHD*D;
    int k = threadIdx.x, n = blockIdx.x;
    dst[((size_t)e*D + n)*HHD + k] = f2bf(src[k*D + n]);
}

__global__ __launch_bounds__(256) void prep_bw_kernel(const float* __restrict__ src,
                                                      unsigned short* __restrict__ dst){
    int k = threadIdx.x, col = blockIdx.x;
    dst[col*D + k] = f2bf(src[k*D + col]);
}

__global__ __launch_bounds__(256) void zero_kernel(float* __restrict__ p, int n){
    int idx = blockIdx.x*256 + threadIdx.x;
    if (idx < n) p[idx] = 0.f;
}

__global__ __launch_bounds__(256) void router_kernel(const float* __restrict__ x,
                                                     const float* __restrict__ rw,
                                                     float* __restrict__ rmask){
    int wave = threadIdx.x >> 6, lane = threadIdx.x & 63;
    int row = blockIdx.x*4 + wave;
    float4 xv = ((const float4*)(x + (size_t)row*D))[lane];
    int f = lane*4;
    float xa[4] = {xv.x, xv.y, xv.z, xv.w};
    float p0 = 0.f, p1 = 0.f, p2 = 0.f;
    #pragma unroll
    for (int j = 0; j < 4; j++){
        p0 += xa[j]*rw[(f+j)*NE + 0];
        p1 += xa[j]*rw[(f+j)*NE + 1];
        p2 += xa[j]*rw[(f+j)*NE + 2];
    }
    for (int off = 32; off; off >>= 1){
        p0 += __shfl_down(p0, off);
        p1 += __shfl_down(p1, off);
        p2 += __shfl_down(p2, off);
    }
    if (lane == 0){
        float p[3] = {p0, p1, p2};
        int ex = 0;
        for (int e = 1; e < NE; e++) if (p[e] <= p[ex]) ex = e;
        for (int e = 0; e < NE; e++) rmask[e*ROWS + row] = (e == ex) ? 0.f : 1.f;
    }
}

// ---------- GEMM1 (x@W1, transposed out) + fused es/ed + colmean ----------
// grid (HHD/64=H, ROWS/64, 4experts)
__global__ __launch_bounds__(256) void gemm1_kernel(const unsigned short* __restrict__ w1nk,
                                                    const unsigned short* __restrict__ featbf,
                                                    const float* __restrict__ rmask,
                                                    const float* __restrict__ main_a1s,
                                                    const float* __restrict__ main_a1d,
                                                    const float* __restrict__ dep_a1s,
                                                    const float* __restrict__ dep_a1d,
                                                    unsigned short* __restrict__ ht4,
                                                    float* __restrict__ es4,
                                                    float* __restrict__ ed4,
                                                    float* __restrict__ meanV1){
    __shared__ float ep[2][64][17];
    int tid = threadIdx.x, wave = tid >> 6, lane = tid & 63;
    int quad = lane >> 4, l16 = lane & 15;
    int e = blockIdx.z;
    int m0 = blockIdx.x*64;         // head h = blockIdx.x
    int n0 = blockIdx.y*64;
    const unsigned short* arow = w1nk + (size_t)e*HHD*D + (size_t)(m0 + wave*16 + l16)*D + quad*8;
    const unsigned short* brow[4];
    bool zr[4];
    #pragma unroll
    for (int j = 0; j < 4; j++){
        int n = n0 + j*16 + l16;
        brow[j] = featbf + (size_t)n*D + quad*8;
        zr[j] = (e > 0) ? (rmask[(size_t)(e-1)*ROWS + n] == 0.f) : false;
    }
    f32x4 z4 = {0.f,0.f,0.f,0.f};
    f32x4 acc[4] = {z4, z4, z4, z4};
    bf8_t bz = {0,0,0,0,0,0,0,0};
    for (int k0 = 0; k0 < D; k0 += 32){
        bf8_t a = *(const bf8_t*)(arow + k0);
        #pragma unroll
        for (int j = 0; j < 4; j++){
            bf8_t bv = zr[j] ? bz : *(const bf8_t*)(brow[j] + k0);
            acc[j] = __builtin_amdgcn_mfma_f32_16x16x32_bf16(a, bv, acc[j], 0, 0, 0);
        }
    }
    int b = n0 >> 10;
    int mbase = m0 + wave*16 + quad*4;
    unsigned short* htb = ht4 + (size_t)e*B*HHD*S;
    #pragma unroll
    for (int j = 0; j < 4; j++){
        int s = (n0 + j*16 + l16) & 1023;
        #pragma unroll
        for (int r = 0; r < 4; r++)
            htb[((size_t)b*HHD + mbase + r)*S + s] = f2bf(acc[j][r]);
    }
    const float* a1sp = (e == 0) ? main_a1s : dep_a1s + (size_t)(e-1)*H*HD;
    const float* a1dp = (e == 0) ? main_a1d : dep_a1d + (size_t)(e-1)*H*HD;
    float a1sv[4], a1dv[4];
    #pragma unroll
    for (int r = 0; r < 4; r++){ a1sv[r] = a1sp[mbase + r]; a1dv[r] = a1dp[mbase + r]; }
    #pragma unroll
    for (int j = 0; j < 4; j++){
        float ps = 0.f, pd = 0.f;
        #pragma unroll
        for (int r = 0; r < 4; r++){ ps += acc[j][r]*a1sv[r]; pd += acc[j][r]*a1dv[r]; }
        ep[0][j*16 + l16][wave*4 + quad] = ps;
        ep[1][j*16 + l16][wave*4 + quad] = pd;
    }
    #pragma unroll
    for (int r = 0; r < 4; r++){
        float cm = acc[0][r] + acc[1][r] + acc[2][r] + acc[3][r];
        for (int off = 8; off; off >>= 1) cm += __shfl_down(cm, off, 16);
        if (l16 == 0)
            atomicAdd(meanV1 + ((size_t)e*B + b)*HHD + mbase + r, cm*(1.f/(float)S));
    }
    __syncthreads();
    if (tid < 128){
        int arr = tid >> 6, s = tid & 63;
        float sum = 0.f;
        #pragma unroll
        for (int i = 0; i < 16; i++) sum += ep[arr][s][i];
        int n = n0 + s;
        float* dst = arr ? ed4 : es4;
        dst[(((size_t)e*B + (n >> 10))*H + blockIdx.x)*S + (n & 1023)] = sum;
    }
}

// ---------- GEMM2 (h1@W2, transposed out) + fused f2s/f2d + colmean ----------
// grid (D/64=4, ROWS/64, 4experts)
__global__ __launch_bounds__(256) void gemm2_kernel(const unsigned short* __restrict__ w2nk,
                                                    const unsigned short* __restrict__ h1c4,
                                                    const float* __restrict__ main_a2s,
                                                    const float* __restrict__ main_a2d,
                                                    const float* __restrict__ dep_a2s,
                                                    const float* __restrict__ dep_a2d,
                                                    unsigned short* __restrict__ h2t4,
                                                    float* __restrict__ f2s4,
                                                    float* __restrict__ f2d4,
                                                    float* __restrict__ meanV2){
    __shared__ float ep[2][64][17];
    int tid = threadIdx.x, wave = tid >> 6, lane = tid & 63;
    int quad = lane >> 4, l16 = lane & 15;
    int e = blockIdx.z;
    int m0 = blockIdx.x*64;
    int n0 = blockIdx.y*64;
    const unsigned short* arow = w2nk + (size_t)e*D*HHD + (size_t)(m0 + wave*16 + l16)*HHD + quad*8;
    const unsigned short* brow[4];
    #pragma unroll
    for (int j = 0; j < 4; j++)
        brow[j] = h1c4 + (size_t)e*ROWS*HHD + (size_t)(n0 + j*16 + l16)*HHD + quad*8;
    f32x4 z4 = {0.f,0.f,0.f,0.f};
    f32x4 acc[4] = {z4, z4, z4, z4};
    for (int k0 = 0; k0 < HHD; k0 += 32){
        bf8_t a = *(const bf8_t*)(arow + k0);
        #pragma unroll
        for (int j = 0; j < 4; j++){
            bf8_t bv = *(const bf8_t*)(brow[j] + k0);
            acc[j] = __builtin_amdgcn_mfma_f32_16x16x32_bf16(a, bv, acc[j], 0, 0, 0);
        }
    }
    int b = n0 >> 10;
    int mbase = m0 + wave*16 + quad*4;
    unsigned short* h2b = h2t4 + (size_t)e*B*D*S;
    #pragma unroll
    for (int j = 0; j < 4; j++){
        int s = (n0 + j*16 + l16) & 1023;
        #pragma unroll
        for (int r = 0; r < 4; r++)
            h2b[((size_t)b*D + mbase + r)*S + s] = f2bf(acc[j][r]);
    }
    const float* a2sp = (e == 0) ? main_a2s : dep_a2s + (size_t)(e-1)*D;
    const float* a2dp = (e == 0) ? main_a2d : dep_a2d + (size_t)(e-1)*D;
    float a2sv[4], a2dv[4];
    #pragma unroll
    for (int r = 0; r < 4; r++){ a2sv[r] = a2sp[mbase + r]; a2dv[r] = a2dp[mbase + r]; }
    #pragma unroll
    for (int j = 0; j < 4; j++){
        float ps = 0.f, pd = 0.f;
        #pragma unroll
        for (int r = 0; r < 4; r++){ ps += acc[j][r]*a2sv[r]; pd += acc[j][r]*a2dv[r]; }
        ep[0][j*16 + l16][wave*4 + quad] = ps;
        ep[1][j*16 + l16][wave*4 + quad] = pd;
    }
    #pragma unroll
    for (int r = 0; r < 4; r++){
        float cm = acc[0][r] + acc[1][r] + acc[2][r] + acc[3][r];
        for (int off = 8; off; off >>= 1) cm += __shfl_down(cm, off, 16);
        if (l16 == 0)
            atomicAdd(meanV2 + ((size_t)e*B + b)*D + mbase + r, cm*(1.f/(float)S));
    }
    __syncthreads();
    if (tid < 128){
        int arr = tid >> 6, s = tid & 63;
        float sum = 0.f;
        #pragma unroll
        for (int i = 0; i < 16; i++) sum += ep[arr][s][i];
        int n = n0 + s;
        float* dst = arr ? f2d4 : f2s4;
        atomicAdd(dst + (size_t)e*ROWS + n, sum);
    }
}

// ---------- attn1: one head per block, single weight phase, chunk-range skip ----------
// grid (S/16, H, 4experts*B)
__global__ __launch_bounds__(256) void attn1_kernel(const unsigned short* __restrict__ ht4,
                                                    const float* __restrict__ es4,
                                                    const float* __restrict__ ed4,
                                                    const unsigned char* __restrict__ adjm,
                                                    const float* __restrict__ meanV1,
                                                    unsigned short* __restrict__ h1c4,
                                                    const int* __restrict__ doc_p,
                                                    const int* __restrict__ sect_p){
    __shared__ unsigned short aw[16][1032];    // pad: row stride 516 words -> 4-bank shift (2-way, free)
    __shared__ float dpart[16][17];
    __shared__ float denom[16];
    int tid = threadIdx.x, wave = tid >> 6, lane = tid & 63;
    int quad = lane >> 4, l16 = lane & 15;
    int s0 = blockIdx.x*16, h = blockIdx.y;
    int e = blockIdx.z >> 2, b = blockIdx.z & 3;
    int tlo = 0, thi = S;
    int ex = e - 1;
    if (ex == 0){ thi = S - *sect_p - *doc_p; }
    else if (ex == 1){ tlo = S - *sect_p - *doc_p; thi = S - *doc_p; }
    else if (ex == 2){ tlo = S - *doc_p; }
    int clo = tlo >> 6, chi = (thi + 63) >> 6;

    int wr = tid >> 4, q = tid & 15;
    float es_r = es4[(((size_t)e*B + b)*H + h)*S + s0 + wr];
    const unsigned char* adjrow = adjm + ((size_t)(b*S + s0 + wr))*S;
    const float* edrow = ed4 + (((size_t)e*B + b)*H + h)*S;
    float dreg = 0.f;
    #pragma unroll 4
    for (int c = clo; c < chi; c++){
        int t = c*64 + q*4;
        uchar4 am = *(const uchar4*)(adjrow + t);
        float4 ev = *(const float4*)(edrow + t);
        unsigned char av[4] = {am.x, am.y, am.z, am.w};
        float e4[4] = {ev.x, ev.y, ev.z, ev.w};
        ushort4 wv;
        unsigned short* wp = (unsigned short*)&wv;
        #pragma unroll
        for (int j = 0; j < 4; j++){
            int tj = t + j;
            bool msk = (tj >= tlo) && (tj < thi) && (av[j] != 0);
            float w = msk ? __expf(leaky(es_r + e4[j])) : 0.f;
            dreg += w;
            wp[j] = f2bf(w);
        }
        *(ushort4*)(&aw[wr][t & 1023]) = wv;
    }
    dpart[wr][q] = dreg;
    __syncthreads();
    if (tid < 16){
        float s = 0.f;
        #pragma unroll
        for (int j = 0; j < 16; j++) s += dpart[tid][j];
        denom[tid] = s;
    }
    // MFMA phase: uninterrupted
    const unsigned short* bbase = ht4 + (((size_t)e*B + b)*HHD + h*64 + wave*16 + l16)*S;
    f32x4 acc = {0.f,0.f,0.f,0.f};
    for (int c = clo; c < chi; c++){
        #pragma unroll
        for (int kk = 0; kk < 2; kk++){
            int t = c*64 + kk*32 + quad*8;
            bf8_t a = *(const bf8_t*)(&aw[l16][t & 1023]);
            bf8_t bv = *(const bf8_t*)(bbase + t);
            acc = __builtin_amdgcn_mfma_f32_16x16x32_bf16(a, bv, acc, 0, 0, 0);
        }
    }
    __syncthreads();   // denom visible to all
    int col = h*64 + wave*16 + l16;
    #pragma unroll
    for (int r = 0; r < 4; r++){
        int row = quad*4 + r;
        float dn = denom[row];
        float v = (dn > 0.f) ? acc[r]/dn : meanV1[((size_t)e*B + b)*HHD + col];
        v = v > 0.f ? v : __expf(v) - 1.f;   // ELU
        h1c4[(size_t)e*ROWS*HHD + ((size_t)(b*S + s0 + row))*HHD + col] = f2bf(v);
    }
}

// ---------- attn2: 128-col tile per block, single weight phase, chunk-range skip ----------
// grid (S/16, D/128=2, 4experts*B)
__global__ __launch_bounds__(256) void attn2_kernel(const unsigned short* __restrict__ h2t4,
                                                    const float* __restrict__ f2s4,
                                                    const float* __restrict__ f2d4,
                                                    const unsigned char* __restrict__ adjm,
                                                    const float* __restrict__ meanV2,
                                                    float* __restrict__ mainO,
                                                    unsigned short* __restrict__ depO3,
                                                    const int* __restrict__ doc_p,
                                                    const int* __restrict__ sect_p){
    __shared__ unsigned short aw[16][1032];
    __shared__ float dpart[16][17];
    __shared__ float denom[16];
    int tid = threadIdx.x, wave = tid >> 6, lane = tid & 63;
    int quad = lane >> 4, l16 = lane & 15;
    int s0 = blockIdx.x*16, n0 = blockIdx.y*128;
    int e = blockIdx.z >> 2, b = blockIdx.z & 3;
    int tlo = 0, thi = S;
    int ex = e - 1;
    if (ex == 0){ thi = S - *sect_p - *doc_p; }
    else if (ex == 1){ tlo = S - *sect_p - *doc_p; thi = S - *doc_p; }
    else if (ex == 2){ tlo = S - *doc_p; }
    int clo = tlo >> 6, chi = (thi + 63) >> 6;

    int wr = tid >> 4, q = tid & 15;
    float fs_r = f2s4[(size_t)e*ROWS + b*S + s0 + wr];
    const unsigned char* adjrow = adjm + ((size_t)(b*S + s0 + wr))*S;
    const float* fdrow = f2d4 + (size_t)e*ROWS + b*S;
    float dreg = 0.f;
    #pragma unroll 4
    for (int c = clo; c < chi; c++){
        int t = c*64 + q*4;
        uchar4 am = *(const uchar4*)(adjrow + t);
        float4 ev = *(const float4*)(fdrow + t);
        unsigned char av[4] = {am.x, am.y, am.z, am.w};
        float e4[4] = {ev.x, ev.y, ev.z, ev.w};
        ushort4 wv;
        unsigned short* wp = (unsigned short*)&wv;
        #pragma unroll
        for (int j = 0; j < 4; j++){
            int tj = t + j;
            bool msk = (tj >= tlo) && (tj < thi) && (av[j] != 0);
            float w = msk ? __expf(leaky(fs_r + e4[j])) : 0.f;
            dreg += w;
            wp[j] = f2bf(w);
        }
        *(ushort4*)(&aw[wr][t & 1023]) = wv;
    }
    dpart[wr][q] = dreg;
    __syncthreads();
    if (tid < 16){
        float s = 0.f;
        #pragma unroll
        for (int j = 0; j < 16; j++) s += dpart[tid][j];
        denom[tid] = s;
    }
    // MFMA phase: each wave handles 2 col tiles (32 cols)
    const unsigned short* bbase0 = h2t4 + (((size_t)e*B + b)*D + n0 + wave*32 + l16)*S;
    const unsigned short* bbase1 = bbase0 + (size_t)16*S;
    f32x4 acc0 = {0.f,0.f,0.f,0.f}, acc1 = {0.f,0.f,0.f,0.f};
    for (int c = clo; c < chi; c++){
        #pragma unroll
        for (int kk = 0; kk < 2; kk++){
            int t = c*64 + kk*32 + quad*8;
            bf8_t a = *(const bf8_t*)(&aw[l16][t & 1023]);
            bf8_t b0 = *(const bf8_t*)(bbase0 + t);
            bf8_t b1 = *(const bf8_t*)(bbase1 + t);
            acc0 = __builtin_amdgcn_mfma_f32_16x16x32_bf16(a, b0, acc0, 0, 0, 0);
            acc1 = __builtin_amdgcn_mfma_f32_16x16x32_bf16(a, b1, acc1, 0, 0, 0);
        }
    }
    __syncthreads();
    #pragma unroll
    for (int jt = 0; jt < 2; jt++){
        f32x4 acc = jt ? acc1 : acc0;
        int col = n0 + wave*32 + jt*16 + l16;
        #pragma unroll
        for (int r = 0; r < 4; r++){
            int row = quad*4 + r;
            float dn = denom[row];
            float v = (dn > 0.f) ? acc[r]/dn : meanV2[((size_t)e*B + b)*D + col];
            size_t idx = ((size_t)(b*S + s0 + row))*D + col;
            if (e == 0) mainO[idx] = v;
            else        depO3[(size_t)(e-1)*ROWS*D + idx] = f2bf(v);
        }
    }
}

// ---------- blend ----------
__global__ __launch_bounds__(256) void blend_mfma_kernel(const unsigned short* __restrict__ featbf,
                                                         const unsigned short* __restrict__ bwt,
                                                         const float* __restrict__ bb,
                                                         const float* __restrict__ mainO,
                                                         const unsigned short* __restrict__ depO3,
                                                         const float* __restrict__ rmask,
                                                         float* __restrict__ outp,
                                                         float* __restrict__ sumBuf){
    __shared__ float red[256];
    int tid = threadIdx.x, wave = tid >> 6, lane = tid & 63;
    int quad = lane >> 4, l16 = lane & 15;
    int m0 = blockIdx.x*64, n0 = blockIdx.y*64;
    const unsigned short* arow = featbf + (size_t)(m0 + wave*16 + l16)*D + quad*8;
    const unsigned short* brow[4];
    #pragma unroll
    for (int j = 0; j < 4; j++)
        brow[j] = bwt + (size_t)(n0 + j*16 + l16)*D + quad*8;
    f32x4 z4 = {0.f,0.f,0.f,0.f};
    f32x4 acc[4] = {z4, z4, z4, z4};
    for (int k0 = 0; k0 < D; k0 += 32){
        bf8_t a = *(const bf8_t*)(arow + k0);
        #pragma unroll
        for (int j = 0; j < 4; j++){
            bf8_t bv = *(const bf8_t*)(brow[j] + k0);
            acc[j] = __builtin_amdgcn_mfma_f32_16x16x32_bf16(a, bv, acc[j], 0, 0, 0);
        }
    }
    float lsum = 0.f;
    int mbase = m0 + wave*16 + quad*4;
    float rm[4][3];
    #pragma unroll
    for (int r = 0; r < 4; r++)
        #pragma unroll
        for (int e0 = 0; e0 < 3; e0++)
            rm[r][e0] = rmask[(size_t)e0*ROWS + mbase + r];
    #pragma unroll
    for (int j = 0; j < 4; j++){
        int col = n0 + j*16 + l16;
        float bias = bb[col];
        #pragma unroll
        for (int r = 0; r < 4; r++){
            size_t idx = (size_t)(mbase + r)*D + col;
            float dep = 0.f;
            #pragma unroll
            for (int e0 = 0; e0 < 3; e0++)
                dep += rm[r][e0]*bf2f(depO3[(size_t)e0*ROWS*D + idx]);
            float bw = 1.f/(1.f + __expf(-(acc[j][r] + bias)));
            lsum += bw;
            outp[idx] = bw*mainO[idx] + (1.f - bw)*dep;
        }
    }
    red[tid] = lsum;
    __syncthreads();
    for (int sft = 128; sft; sft >>= 1){
        if (tid < sft) red[tid] += red[tid + sft];
        __syncthreads();
    }
    if (tid == 0) atomicAdd(sumBuf, red[0]);
}

__global__ void finalize_kernel(const float* __restrict__ sumBuf, float* __restrict__ outp){
    float mc = *sumBuf / (float)(ROWS*D);
    outp[ROWS*D]     = fabsf(mc - 0.6f)*0.01f;
    outp[ROWS*D + 1] = mc;
}

extern "C" void kernel_launch(void* const* d_in, const int* in_sizes, int n_in,
                              void* d_out, int out_size, void* d_ws, size_t ws_size,
                              hipStream_t stream)
{
    const float* feature  = (const float*)d_in[0];
    const float* adj      = (const float*)d_in[1];
    const float* main_W1  = (const float*)d_in[2];
    const float* main_a1s = (const float*)d_in[3];
    const float* main_a1d = (const float*)d_in[4];
    const float* main_W2  = (const float*)d_in[5];
    const float* main_a2s = (const float*)d_in[6];
    const float* main_a2d = (const float*)d_in[7];
    const float* dep_W1   = (const float*)d_in[8];
    const float* dep_a1s  = (const float*)d_in[9];
    const float* dep_a1d  = (const float*)d_in[10];
    const float* dep_W2   = (const float*)d_in[11];
    const float* dep_a2s  = (const float*)d_in[12];
    const float* dep_a2d  = (const float*)d_in[13];
    const float* router_W = (const float*)d_in[14];
    const float* blend_W  = (const float*)d_in[15];
    const float* blend_b  = (const float*)d_in[16];
    const int*   doc_p    = (const int*)d_in[17];
    const int*   sect_p   = (const int*)d_in[18];

    char* ws = (char*)d_ws;
    size_t off = 0;
    unsigned short* featbf = (unsigned short*)(ws + off); off += (size_t)ROWS*D*2;       // 2 MB
    unsigned char*  adjm   = (unsigned char*)(ws + off);  off += (size_t)B*S*S;          // 4 MB
    unsigned short* w1nk   = (unsigned short*)(ws + off); off += (size_t)4*HHD*D*2;
    unsigned short* w2nk   = (unsigned short*)(ws + off); off += (size_t)4*D*HHD*2;
    unsigned short* bwt    = (unsigned short*)(ws + off); off += (size_t)D*D*2;
    unsigned short* ht4    = (unsigned short*)(ws + off); off += (size_t)4*B*HHD*S*2;    // 12 MB
    unsigned short* h2t4   = ht4;                          // alias: ht dead before gemm2 writes
    unsigned short* h1c4   = (unsigned short*)(ws + off); off += (size_t)4*ROWS*HHD*2;   // 12 MB
    float* mainO  = (float*)h1c4;                          // alias: h1c dead before attn2 writes
    unsigned short* depO3 = (unsigned short*)((char*)h1c4 + (size_t)ROWS*D*4);
    float* es4    = (float*)(ws + off); off += (size_t)4*B*H*S*4;
    float* ed4    = (float*)(ws + off); off += (size_t)4*B*H*S*4;
    // contiguous zero region:
    float* f2s4   = (float*)(ws + off); off += (size_t)4*ROWS*4;
    float* f2d4   = (float*)(ws + off); off += (size_t)4*ROWS*4;
    float* meanV1 = (float*)(ws + off); off += (size_t)4*B*HHD*4;
    float* meanV2 = (float*)(ws + off); off += (size_t)4*B*D*4;
    float* sumBuf = (float*)(ws + off); off += 64;
    const int nzero = 4*ROWS + 4*ROWS + 4*B*HHD + 4*B*D + 16;
    float* rmask  = (float*)(ws + off); off += (size_t)NE*ROWS*4;
    float* outp   = (float*)d_out;

    conv_feat_kernel<<<ROWS*D/4/256, 256, 0, stream>>>(feature, featbf);
    conv_adj_kernel<<<B*S*S/4/256, 256, 0, stream>>>(adj, adjm);
    prep_w1_kernel<<<dim3(HHD*D/256, 4), 256, 0, stream>>>(main_W1, dep_W1, w1nk);
    prep_w2_kernel<<<dim3(D, 4), HHD, 0, stream>>>(main_W2, dep_W2, w2nk);
    prep_bw_kernel<<<D, D, 0, stream>>>(blend_W, bwt);
    zero_kernel<<<(nzero + 255)/256, 256, 0, stream>>>(f2s4, nzero);
    router_kernel<<<ROWS/4, 256, 0, stream>>>(feature, router_W, rmask);

    gemm1_kernel<<<dim3(H, ROWS/64, 4), 256, 0, stream>>>(w1nk, featbf, rmask,
        main_a1s, main_a1d, dep_a1s, dep_a1d, ht4, es4, ed4, meanV1);
    attn1_kernel<<<dim3(S/16, H, 4*B), 256, 0, stream>>>(ht4, es4, ed4, adjm, meanV1,
        h1c4, doc_p, sect_p);
    gemm2_kernel<<<dim3(D/64, ROWS/64, 4), 256, 0, stream>>>(w2nk, h1c4,
        main_a2s, main_a2d, dep_a2s, dep_a2d, h2t4, f2s4, f2d4, meanV2);
    attn2_kernel<<<dim3(S/16, D/128, 4*B), 256, 0, stream>>>(h2t4, f2s4, f2d4, adjm, meanV2,
        mainO, depO3, doc_p, sect_p);

    blend_mfma_kernel<<<dim3(ROWS/64, D/64), 256, 0, stream>>>(featbf, bwt, blend_b,
        mainO, depO3, rmask, outp, sumBuf);
    finalize_kernel<<<1, 1, 0, stream>>>(sumBuf, outp);
}